// Round 1
// baseline (1325.951 us; speedup 1.0000x reference)
//
#include <hip/hip_runtime.h>
#include <hip/hip_bf16.h>
#include <cstdint>
#include <cstddef>

#define B_ 64
#define N_ 4096
#define D_ 256
#define S_ 11
#define K_ 128
#define H_ 256
#define ITERS_ 3
#define EPS_ 1e-6f
#define LN_EPS_ 1e-5f
#define SCALE_ 0.08838834764831845f   // 128^-0.5

typedef __bf16 bf16x8 __attribute__((ext_vector_type(8)));
typedef float  f32x4  __attribute__((ext_vector_type(4)));

__device__ __forceinline__ float b2f(unsigned int u16) {
  return __builtin_bit_cast(float, (u16 & 0xffffu) << 16);
}
__device__ __forceinline__ unsigned short f2bu(float f) {
  unsigned int u = __builtin_bit_cast(unsigned int, f);
  u += 0x7fffu + ((u >> 16) & 1u);   // round-to-nearest-even
  return (unsigned short)(u >> 16);
}

// ---------------- K0: cast Wk|Wv -> W2 bf16 [256][256] ----------------
__global__ __launch_bounds__(256) void k0_wcast(const float* __restrict__ Wk,
                                                const float* __restrict__ Wv,
                                                unsigned short* __restrict__ W2) {
  int i = blockIdx.x * 256 + threadIdx.x;        // 65536
  int j = i >> 8, d = i & 255;
  float v = (j < 128) ? Wk[j * 256 + d] : Wv[(j - 128) * 256 + d];
  W2[i] = f2bu(v);
}

// ---------------- K_init: slots = mu + exp(log_sigma)*init ----------------
__global__ __launch_bounds__(256) void k_init(const float* __restrict__ si,
                                              const float* __restrict__ mu,
                                              const float* __restrict__ ls,
                                              float* __restrict__ slots) {
  int i = blockIdx.x * 256 + threadIdx.x;        // 90112 exact
  int k = i & 127;
  slots[i] = mu[k] + __expf(ls[k]) * si[i];
}

// ---------------- K1: LayerNorm(inputs) -> x_ln bf16, 1 wave per row ----------------
__global__ __launch_bounds__(256) void k1_ln(const float* __restrict__ x,
                                             const float* __restrict__ w,
                                             const float* __restrict__ bb,
                                             unsigned short* __restrict__ xln) {
  int wave = threadIdx.x >> 6, lane = threadIdx.x & 63;
  long row = (long)blockIdx.x * 4 + wave;
  const float4 xv = *(const float4*)(x + row * 256 + lane * 4);
  float s  = xv.x + xv.y + xv.z + xv.w;
  float sq = xv.x * xv.x + xv.y * xv.y + xv.z * xv.z + xv.w * xv.w;
#pragma unroll
  for (int o = 1; o < 64; o <<= 1) { s += __shfl_xor(s, o); sq += __shfl_xor(sq, o); }
  float mean = s * (1.f / 256.f);
  float var  = sq * (1.f / 256.f) - mean * mean;
  float rstd = rsqrtf(var + LN_EPS_);
  const float4 wv = *(const float4*)(w + lane * 4);
  const float4 bv = *(const float4*)(bb + lane * 4);
  ushort4 o4;
  o4.x = f2bu((xv.x - mean) * rstd * wv.x + bv.x);
  o4.y = f2bu((xv.y - mean) * rstd * wv.y + bv.y);
  o4.z = f2bu((xv.z - mean) * rstd * wv.z + bv.z);
  o4.w = f2bu((xv.w - mean) * rstd * wv.w + bv.w);
  *(ushort4*)(xln + row * 256 + lane * 4) = o4;
}

// ---------------- K2: GEMM  kv[M,256] = x_ln[M,256] * W2^T  (bf16 MFMA) ----------------
// BM=128, BN=128, BK=64, 256 thr = 4 waves (2x2), wave tile 64x64 = 4x4 frags 16x16
__global__ __launch_bounds__(256) void k2_gemm(const unsigned short* __restrict__ A,
                                               const unsigned short* __restrict__ Bt,
                                               unsigned short* __restrict__ C) {
  __shared__ unsigned short As[128 * 64];
  __shared__ unsigned short Bs[128 * 64];
  const int bid = blockIdx.x;
  const int bn = bid & 1, bm = bid >> 1;
  const int t = threadIdx.x;
  const int lane = t & 63, wave = t >> 6;
  const int wm = wave >> 1, wn = wave & 1;
  const int srow = t >> 3;            // 0..31
  const int scol = (t & 7) * 8;       // 0,8,..56
  const long arow0 = (long)bm * 128;

  f32x4 acc[4][4] = {};
  uint4 ra[4], rb[4];

  auto loadA = [&](int kt, uint4* r) {
#pragma unroll
    for (int p = 0; p < 4; p++) {
      long row = arow0 + p * 32 + srow;
      r[p] = *(const uint4*)(A + row * 256 + kt * 64 + scol);
    }
  };
  auto loadB = [&](int kt, uint4* r) {
#pragma unroll
    for (int p = 0; p < 4; p++) {
      int row = bn * 128 + p * 32 + srow;
      r[p] = *(const uint4*)(Bt + row * 256 + kt * 64 + scol);
    }
  };

  loadA(0, ra); loadB(0, rb);
#pragma unroll
  for (int kt = 0; kt < 4; kt++) {
#pragma unroll
    for (int p = 0; p < 4; p++) {
      *(uint4*)&As[(p * 32 + srow) * 64 + scol] = ra[p];
      *(uint4*)&Bs[(p * 32 + srow) * 64 + scol] = rb[p];
    }
    __syncthreads();
    if (kt < 3) { loadA(kt + 1, ra); loadB(kt + 1, rb); }
#pragma unroll
    for (int kk = 0; kk < 2; kk++) {
      bf16x8 af[4], bfr[4];
#pragma unroll
      for (int i = 0; i < 4; i++)
        af[i] = *(const bf16x8*)&As[(wm * 64 + i * 16 + (lane & 15)) * 64 + kk * 32 + (lane >> 4) * 8];
#pragma unroll
      for (int j = 0; j < 4; j++)
        bfr[j] = *(const bf16x8*)&Bs[(wn * 64 + j * 16 + (lane & 15)) * 64 + kk * 32 + (lane >> 4) * 8];
#pragma unroll
      for (int i = 0; i < 4; i++)
#pragma unroll
        for (int j = 0; j < 4; j++)
          acc[i][j] = __builtin_amdgcn_mfma_f32_16x16x32_bf16(af[i], bfr[j], acc[i][j], 0, 0, 0);
    }
    __syncthreads();
  }
#pragma unroll
  for (int i = 0; i < 4; i++)
#pragma unroll
    for (int j = 0; j < 4; j++)
#pragma unroll
      for (int r = 0; r < 4; r++) {
        long row = (long)bm * 128 + wm * 64 + i * 16 + (lane >> 4) * 4 + r;
        int col = bn * 128 + wn * 64 + j * 16 + (lane & 15);
        C[row * 256 + col] = f2bu(acc[i][j][r]);
      }
}

// ---------------- reduce helper: sum over 128 threads ----------------
__device__ __forceinline__ float redsum128(float v, float* red2) {
#pragma unroll
  for (int o = 1; o < 64; o <<= 1) v += __shfl_xor(v, o);
  __syncthreads();
  if ((threadIdx.x & 63) == 0) red2[threadIdx.x >> 6] = v;
  __syncthreads();
  return red2[0] + red2[1];
}

// ---------------- K3: sn = LN(slots); q = sn * Wq^T ----------------
__global__ __launch_bounds__(128) void k3_q(const float* __restrict__ slots,
                                            const float* __restrict__ lw,
                                            const float* __restrict__ lb,
                                            const float* __restrict__ Wq,
                                            float* __restrict__ q) {
  int b = blockIdx.x, j = threadIdx.x;
  __shared__ float sn[128];
  __shared__ float red2[2];
  for (int s = 0; s < S_; s++) {
    float x = slots[((size_t)b * S_ + s) * 128 + j];
    float sum = redsum128(x, red2);
    float sq  = redsum128(x * x, red2);
    float mean = sum * (1.f / 128.f);
    float var  = sq * (1.f / 128.f) - mean * mean;
    float v = (x - mean) * rsqrtf(var + LN_EPS_) * lw[j] + lb[j];
    sn[j] = v;
    __syncthreads();
    float acc = 0.f;
#pragma unroll 8
    for (int kk = 0; kk < 128; kk++) acc += sn[kk] * Wq[j * 128 + kk];
    q[((size_t)b * S_ + s) * 128 + j] = acc;
    __syncthreads();
  }
}

// ---------------- K4: logits + softmax + EPS -> attn_t[B][S][N], den partials ----------------
__global__ __launch_bounds__(256) void k4_attn(const unsigned short* __restrict__ kv,
                                               const float* __restrict__ qg,
                                               float* __restrict__ attn_t,
                                               float* __restrict__ den_part) {
  int blk = blockIdx.x;
  int b = blk >> 3, tile = blk & 7;
  int t = threadIdx.x;
  __shared__ float qs[S_][128];
  __shared__ float red[S_][256];
  for (int i = t; i < S_ * 128; i += 256) qs[i >> 7][i & 127] = qg[(size_t)b * S_ * 128 + i];
  __syncthreads();

  float dloc[S_];
#pragma unroll
  for (int s = 0; s < S_; s++) dloc[s] = 0.f;

  for (int rep = 0; rep < 2; rep++) {
    int n = tile * 512 + rep * 256 + t;
    const unsigned short* krow = kv + ((size_t)b * N_ + n) * 256;
    float lg[S_];
#pragma unroll
    for (int s = 0; s < S_; s++) lg[s] = 0.f;
#pragma unroll 2
    for (int c = 0; c < 16; c++) {
      uint4 kc = *(const uint4*)(krow + c * 8);
      float xf0 = b2f(kc.x), xf1 = b2f(kc.x >> 16);
      float xf2 = b2f(kc.y), xf3 = b2f(kc.y >> 16);
      float xf4 = b2f(kc.z), xf5 = b2f(kc.z >> 16);
      float xf6 = b2f(kc.w), xf7 = b2f(kc.w >> 16);
#pragma unroll
      for (int s = 0; s < S_; s++) {
        const float4 q0 = *(const float4*)&qs[s][c * 8];
        const float4 q1 = *(const float4*)&qs[s][c * 8 + 4];
        lg[s] += xf0 * q0.x + xf1 * q0.y + xf2 * q0.z + xf3 * q0.w
               + xf4 * q1.x + xf5 * q1.y + xf6 * q1.z + xf7 * q1.w;
      }
    }
    float mx = -1e30f;
#pragma unroll
    for (int s = 0; s < S_; s++) { lg[s] *= SCALE_; mx = fmaxf(mx, lg[s]); }
    float sum = 0.f;
    float e[S_];
#pragma unroll
    for (int s = 0; s < S_; s++) { e[s] = __expf(lg[s] - mx); sum += e[s]; }
    float inv = 1.f / sum;
#pragma unroll
    for (int s = 0; s < S_; s++) {
      float a = e[s] * inv + EPS_;
      attn_t[((size_t)b * S_ + s) * N_ + n] = a;
      dloc[s] += a;
    }
  }
#pragma unroll
  for (int s = 0; s < S_; s++) red[s][t] = dloc[s];
  __syncthreads();
  for (int off = 128; off > 0; off >>= 1) {
    if (t < off)
#pragma unroll
      for (int s = 0; s < S_; s++) red[s][t] += red[s][t + off];
    __syncthreads();
  }
  if (t < S_) den_part[(size_t)blk * S_ + t] = red[t][0];
}

// ---------------- K5: num partials = sum_n attn * v ----------------
__global__ __launch_bounds__(256) void k5_upd(const unsigned short* __restrict__ kv,
                                              const float* __restrict__ attn_t,
                                              float* __restrict__ num_part) {
  int blk = blockIdx.x;
  int b = blk >> 3, chunk = blk & 7;
  int t = threadIdx.x;
  int k = t & 127, sh = t >> 7;
  __shared__ float att[S_][512];
  int n0 = chunk * 512;
  for (int i = t; i < S_ * 512; i += 256) {
    int s = i >> 9, nn = i & 511;
    att[s][nn] = attn_t[((size_t)b * S_ + s) * N_ + n0 + nn];
  }
  __syncthreads();
  int s0 = sh * 6, ns = sh ? 5 : 6;
  float acc[6] = {0, 0, 0, 0, 0, 0};
  const unsigned short* vbase = kv + ((size_t)b * N_ + n0) * 256 + 128 + k;
#pragma unroll 4
  for (int nn = 0; nn < 512; nn++) {
    float v = b2f(vbase[(size_t)nn * 256]);
#pragma unroll
    for (int j = 0; j < 6; j++)
      if (j < ns) acc[j] += att[s0 + j][nn] * v;
  }
  for (int j = 0; j < ns; j++)
    num_part[(((size_t)b * 8 + chunk) * S_ + s0 + j) * 128 + k] = acc[j];
}

// ---------------- K6: finalize updates, GRU, MLP -> slots ----------------
__global__ __launch_bounds__(128) void k6_final(const float* __restrict__ num_part,
                                                const float* __restrict__ den_part,
                                                float* __restrict__ slots,
                                                const float* __restrict__ w_ih,
                                                const float* __restrict__ w_hh,
                                                const float* __restrict__ b_ih,
                                                const float* __restrict__ b_hh,
                                                const float* __restrict__ lmw,
                                                const float* __restrict__ lmb,
                                                const float* __restrict__ w1,
                                                const float* __restrict__ bb1,
                                                const float* __restrict__ w2,
                                                const float* __restrict__ bb2) {
  int bs = blockIdx.x;
  int b = bs / S_, s = bs % S_;
  int j = threadIdx.x;
  __shared__ float u[128], h[128], m[128], hid[256];
  __shared__ float red2[2];

  float den = 0.f;
#pragma unroll
  for (int c = 0; c < 8; c++) den += den_part[((size_t)b * 8 + c) * S_ + s];
  float uj = 0.f;
#pragma unroll
  for (int c = 0; c < 8; c++) uj += num_part[(((size_t)b * 8 + c) * S_ + s) * 128 + j];
  uj /= den;
  float hj = slots[((size_t)b * S_ + s) * 128 + j];
  u[j] = uj; h[j] = hj;
  __syncthreads();

  float gir = b_ih[j], giz = b_ih[128 + j], gin = b_ih[256 + j];
  float ghr = b_hh[j], ghz = b_hh[128 + j], ghn = b_hh[256 + j];
#pragma unroll 4
  for (int kk = 0; kk < 128; kk++) {
    float uk = u[kk], hk = h[kk];
    gir += w_ih[j * 128 + kk] * uk;
    giz += w_ih[(128 + j) * 128 + kk] * uk;
    gin += w_ih[(256 + j) * 128 + kk] * uk;
    ghr += w_hh[j * 128 + kk] * hk;
    ghz += w_hh[(128 + j) * 128 + kk] * hk;
    ghn += w_hh[(256 + j) * 128 + kk] * hk;
  }
  float r = 1.f / (1.f + __expf(-(gir + ghr)));
  float z = 1.f / (1.f + __expf(-(giz + ghz)));
  float nn = tanhf(gin + r * ghn);
  float sj = (1.f - z) * nn + z * hj;

  float sum = redsum128(sj, red2);
  float sq  = redsum128(sj * sj, red2);
  float mean = sum * (1.f / 128.f);
  float var  = sq * (1.f / 128.f) - mean * mean;
  float mj = (sj - mean) * rsqrtf(var + LN_EPS_) * lmw[j] + lmb[j];
  m[j] = mj;
  __syncthreads();

  for (int hh = j; hh < 256; hh += 128) {
    float a = bb1[hh];
#pragma unroll 4
    for (int kk = 0; kk < 128; kk++) a += w1[hh * 128 + kk] * m[kk];
    hid[hh] = fmaxf(a, 0.f);
  }
  __syncthreads();

  float o = sj + bb2[j];
#pragma unroll 4
  for (int hh = 0; hh < 256; hh++) o += w2[j * 256 + hh] * hid[hh];
  slots[((size_t)b * S_ + s) * 128 + j] = o;
}

// ---------------- copy out ----------------
__global__ __launch_bounds__(256) void k_copy(const float* __restrict__ slots,
                                              float* __restrict__ out) {
  int i = blockIdx.x * 256 + threadIdx.x;
  out[i] = slots[i];
}

extern "C" void kernel_launch(void* const* d_in, const int* in_sizes, int n_in,
                              void* d_out, int out_size, void* d_ws, size_t ws_size,
                              hipStream_t stream) {
  (void)in_sizes; (void)n_in; (void)out_size; (void)ws_size;
  const float* inputs     = (const float*)d_in[0];
  const float* slots_init = (const float*)d_in[1];
  const float* slots_mu   = (const float*)d_in[2];
  const float* slots_ls   = (const float*)d_in[3];
  const float* ln_in_w    = (const float*)d_in[4];
  const float* ln_in_b    = (const float*)d_in[5];
  const float* ln_slot_w  = (const float*)d_in[6];
  const float* ln_slot_b  = (const float*)d_in[7];
  const float* ln_mlp_w   = (const float*)d_in[8];
  const float* ln_mlp_b   = (const float*)d_in[9];
  const float* Wq         = (const float*)d_in[10];
  const float* Wk         = (const float*)d_in[11];
  const float* Wv         = (const float*)d_in[12];
  const float* w_ih       = (const float*)d_in[13];
  const float* w_hh       = (const float*)d_in[14];
  const float* b_ih       = (const float*)d_in[15];
  const float* b_hh       = (const float*)d_in[16];
  const float* mlp_w1     = (const float*)d_in[17];
  const float* mlp_b1     = (const float*)d_in[18];
  const float* mlp_w2     = (const float*)d_in[19];
  const float* mlp_b2     = (const float*)d_in[20];

  uintptr_t p = (uintptr_t)d_ws;
  auto carve = [&](size_t bytes) -> void* {
    void* r = (void*)p;
    p += (bytes + 255) & ~(size_t)255;
    return r;
  };
  unsigned short* x_ln = (unsigned short*)carve((size_t)B_ * N_ * D_ * 2);
  unsigned short* kv   = (unsigned short*)carve((size_t)B_ * N_ * 2 * K_ * 2);
  unsigned short* W2   = (unsigned short*)carve((size_t)256 * 256 * 2);
  float* qbuf     = (float*)carve((size_t)B_ * S_ * K_ * 4);
  float* slots    = (float*)carve((size_t)B_ * S_ * K_ * 4);
  float* attn_t   = (float*)carve((size_t)B_ * S_ * N_ * 4);
  float* den_part = (float*)carve((size_t)B_ * 8 * S_ * 4);
  float* num_part = (float*)carve((size_t)B_ * 8 * S_ * K_ * 4);

  k0_wcast<<<256, 256, 0, stream>>>(Wk, Wv, W2);
  k_init<<<(B_ * S_ * K_) / 256, 256, 0, stream>>>(slots_init, slots_mu, slots_ls, slots);
  k1_ln<<<(B_ * N_) / 4, 256, 0, stream>>>(inputs, ln_in_w, ln_in_b, x_ln);
  k2_gemm<<<(B_ * N_ / 128) * 2, 256, 0, stream>>>(x_ln, W2, kv);

  for (int it = 0; it < ITERS_; ++it) {
    k3_q<<<B_, 128, 0, stream>>>(slots, ln_slot_w, ln_slot_b, Wq, qbuf);
    k4_attn<<<B_ * 8, 256, 0, stream>>>(kv, qbuf, attn_t, den_part);
    k5_upd<<<B_ * 8, 256, 0, stream>>>(kv, attn_t, num_part);
    k6_final<<<B_ * S_, 128, 0, stream>>>(num_part, den_part, slots,
                                          w_ih, w_hh, b_ih, b_hh,
                                          ln_mlp_w, ln_mlp_b,
                                          mlp_w1, mlp_b1, mlp_w2, mlp_b2);
  }
  k_copy<<<(B_ * S_ * K_) / 256, 256, 0, stream>>>(slots, (float*)d_out);
}

// Round 2
// 585.173 us; speedup vs baseline: 2.2659x; 2.2659x over previous
//
#include <hip/hip_runtime.h>
#include <hip/hip_bf16.h>
#include <cstdint>
#include <cstddef>

#define B_ 64
#define N_ 4096
#define D_ 256
#define S_ 11
#define K_ 128
#define H_ 256
#define ITERS_ 3
#define EPS_ 1e-6f
#define LN_EPS_ 1e-5f
#define SCALE_ 0.08838834764831845f   // 128^-0.5
#define NCH_ 16                        // n-chunks per batch in k45

typedef __bf16 bf16x8 __attribute__((ext_vector_type(8)));
typedef float  f32x4  __attribute__((ext_vector_type(4)));

__device__ __forceinline__ float b2f(unsigned int u16) {
  return __builtin_bit_cast(float, (u16 & 0xffffu) << 16);
}
__device__ __forceinline__ unsigned short f2bu(float f) {
  unsigned int u = __builtin_bit_cast(unsigned int, f);
  u += 0x7fffu + ((u >> 16) & 1u);   // round-to-nearest-even
  return (unsigned short)(u >> 16);
}
__device__ __forceinline__ unsigned int pk2(float a, float b) {
  return (unsigned int)f2bu(a) | ((unsigned int)f2bu(b) << 16);
}
// async global->LDS, 16B per lane; lds dest must be wave-uniform base
__device__ __forceinline__ void gl16(const void* g, void* l) {
  __builtin_amdgcn_global_load_lds((const __attribute__((address_space(1))) void*)g,
                                   (__attribute__((address_space(3))) void*)l, 16, 0, 0);
}

// ---------------- K0: cast Wk|Wv -> W2 bf16 [256][256] ----------------
__global__ __launch_bounds__(256) void k0_wcast(const float* __restrict__ Wk,
                                                const float* __restrict__ Wv,
                                                unsigned short* __restrict__ W2) {
  int i = blockIdx.x * 256 + threadIdx.x;        // 65536
  int j = i >> 8, d = i & 255;
  float v = (j < 128) ? Wk[j * 256 + d] : Wv[(j - 128) * 256 + d];
  W2[i] = f2bu(v);
}

// ---------------- K_init: slots = mu + exp(log_sigma)*init ----------------
__global__ __launch_bounds__(256) void k_init(const float* __restrict__ si,
                                              const float* __restrict__ mu,
                                              const float* __restrict__ ls,
                                              float* __restrict__ slots) {
  int i = blockIdx.x * 256 + threadIdx.x;        // 90112 exact
  int k = i & 127;
  slots[i] = mu[k] + __expf(ls[k]) * si[i];
}

// ---------------- K12: fused LN(inputs) + GEMM -> kv bf16 ----------------
// BM=64, BN=256 (full), BK=64, 256 thr = 4 waves (N-split), wave tile 64x64.
// A staged via LN in regs -> swizzled LDS; B staged via global_load_lds with
// source-preswizzle (slot = chunk ^ (row&7)); C staged via LDS for coalesced stores.
__global__ __launch_bounds__(256) void k12_lngemm(const float* __restrict__ x,
                                                  const float* __restrict__ lnw,
                                                  const float* __restrict__ lnb,
                                                  const unsigned short* __restrict__ W2,
                                                  unsigned short* __restrict__ kv) {
  __shared__ unsigned short As[64 * 256];   // 32KB (also reused as C staging)
  __shared__ unsigned short Bs[256 * 64];   // 32KB
  const int t = threadIdx.x;
  const int lane = t & 63, w = t >> 6;
  const int bm = blockIdx.x;
  const long rowg0 = (long)bm * 64;

  auto stageB = [&](int kt) {
#pragma unroll
    for (int i = 0; i < 8; i++) {
      int o = i * 4096 + t * 16;             // byte offset in Bs
      int rr = o >> 7;                        // B row (0..255)
      int sl = (o >> 4) & 7;                  // dest chunk slot in row
      int c  = sl ^ (rr & 7);                 // source chunk
      gl16(W2 + rr * 256 + kt * 64 + c * 8,
           (char*)Bs + i * 4096 + w * 1024);
    }
  };

  stageB(0);

  // ---- LN stage: row r = t>>2, quad kq = t&3 owns bf16 chunks kq+4j ----
  const int r = t >> 2, kq = t & 3;
  const float* xrow = x + (rowg0 + r) * 256;
  float4 xa[16];
  float s = 0.f, sq = 0.f;
#pragma unroll
  for (int j = 0; j < 8; j++) {
    int cb = kq + 4 * j;                      // bf16 16B-chunk index 0..31
    xa[2 * j]     = *(const float4*)(xrow + cb * 8);
    xa[2 * j + 1] = *(const float4*)(xrow + cb * 8 + 4);
    float4 a = xa[2 * j], b = xa[2 * j + 1];
    s  += a.x + a.y + a.z + a.w + b.x + b.y + b.z + b.w;
    sq += a.x * a.x + a.y * a.y + a.z * a.z + a.w * a.w
        + b.x * b.x + b.y * b.y + b.z * b.z + b.w * b.w;
  }
  s  += __shfl_xor(s, 1);  s  += __shfl_xor(s, 2);
  sq += __shfl_xor(sq, 1); sq += __shfl_xor(sq, 2);
  float mean = s * (1.f / 256.f);
  float var  = sq * (1.f / 256.f) - mean * mean;
  float rstd = rsqrtf(var + LN_EPS_);
#pragma unroll
  for (int j = 0; j < 8; j++) {
    int cb = kq + 4 * j;
    float4 w0 = *(const float4*)(lnw + cb * 8);
    float4 w1 = *(const float4*)(lnw + cb * 8 + 4);
    float4 b0 = *(const float4*)(lnb + cb * 8);
    float4 b1 = *(const float4*)(lnb + cb * 8 + 4);
    float4 a = xa[2 * j], b = xa[2 * j + 1];
    float y0 = (a.x - mean) * rstd * w0.x + b0.x;
    float y1 = (a.y - mean) * rstd * w0.y + b0.y;
    float y2 = (a.z - mean) * rstd * w0.z + b0.z;
    float y3 = (a.w - mean) * rstd * w0.w + b0.w;
    float y4 = (b.x - mean) * rstd * w1.x + b1.x;
    float y5 = (b.y - mean) * rstd * w1.y + b1.y;
    float y6 = (b.z - mean) * rstd * w1.z + b1.z;
    float y7 = (b.w - mean) * rstd * w1.w + b1.w;
    uint4 u;
    u.x = pk2(y0, y1); u.y = pk2(y2, y3); u.z = pk2(y4, y5); u.w = pk2(y6, y7);
    *(uint4*)((char*)As + r * 512 + (((cb ^ (r & 7))) << 4)) = u;
  }
  __syncthreads();   // As ready; Bs(0) drained (barrier drains vmcnt)

  f32x4 acc[4][4] = {};
#pragma unroll
  for (int kt = 0; kt < 4; kt++) {
#pragma unroll
    for (int kk = 0; kk < 2; kk++) {
      bf16x8 af[4], bfv[4];
#pragma unroll
      for (int i = 0; i < 4; i++) {
        int row = i * 16 + (lane & 15);
        int slot = (kt * 8 + kk * 4 + (lane >> 4)) ^ (lane & 7);
        af[i] = *(const bf16x8*)((const char*)As + row * 512 + (slot << 4));
      }
#pragma unroll
      for (int j = 0; j < 4; j++) {
        int rowb = w * 64 + j * 16 + (lane & 15);
        int slot = (kk * 4 + (lane >> 4)) ^ (lane & 7);
        bfv[j] = *(const bf16x8*)((const char*)Bs + rowb * 128 + (slot << 4));
      }
#pragma unroll
      for (int i = 0; i < 4; i++)
#pragma unroll
        for (int j = 0; j < 4; j++)
          acc[i][j] = __builtin_amdgcn_mfma_f32_16x16x32_bf16(af[i], bfv[j], acc[i][j], 0, 0, 0);
    }
    __syncthreads();                 // done reading Bs
    if (kt < 3) { stageB(kt + 1); __syncthreads(); }
  }

  // ---- epilogue: stage C tile into As (swizzled), then coalesced stores ----
#pragma unroll
  for (int i = 0; i < 4; i++)
#pragma unroll
    for (int j = 0; j < 4; j++)
#pragma unroll
      for (int rr = 0; rr < 4; rr++) {
        int row = i * 16 + (lane >> 4) * 4 + rr;
        int col = w * 64 + j * 16 + (lane & 15);
        *(unsigned short*)((char*)As + row * 512 +
                           ((((col >> 3) ^ (row & 7))) << 4) + ((col & 7) << 1)) =
            f2bu(acc[i][j][rr]);
      }
  __syncthreads();
#pragma unroll
  for (int ch = 0; ch < 8; ch++) {
    int o = ch * 4096 + t * 16;
    int row = o >> 9;
    int c = (o >> 4) & 31;
    uint4 val = *(const uint4*)((const char*)As + row * 512 + ((c ^ (row & 7)) << 4));
    *(uint4*)(kv + (rowg0 + row) * 256 + c * 8) = val;
  }
}

// ---------------- reduce helper: sum over 128 threads ----------------
__device__ __forceinline__ float redsum128(float v, float* red2) {
#pragma unroll
  for (int o = 1; o < 64; o <<= 1) v += __shfl_xor(v, o);
  __syncthreads();
  if ((threadIdx.x & 63) == 0) red2[threadIdx.x >> 6] = v;
  __syncthreads();
  return red2[0] + red2[1];
}

// ---------------- K3: sn = LN(slots); q = sn * Wq^T  (one block per (b,s)) ----------------
__global__ __launch_bounds__(128) void k3_q(const float* __restrict__ slots,
                                            const float* __restrict__ lw,
                                            const float* __restrict__ lb,
                                            const float* __restrict__ Wq,
                                            float* __restrict__ q) {
  int bs = blockIdx.x;
  int j = threadIdx.x;
  __shared__ float sn[128];
  __shared__ float red2[2];
  float x = slots[(size_t)bs * 128 + j];
  float sum = redsum128(x, red2);
  float sq  = redsum128(x * x, red2);
  float mean = sum * (1.f / 128.f);
  float var  = sq * (1.f / 128.f) - mean * mean;
  float v = (x - mean) * rsqrtf(var + LN_EPS_) * lw[j] + lb[j];
  sn[j] = v;
  __syncthreads();
  float acc = 0.f;
#pragma unroll 8
  for (int kk = 0; kk < 128; kk++) acc += sn[kk] * Wq[j * 128 + kk];
  q[(size_t)bs * 128 + j] = acc;
}

// ---------------- K45: fused logits(MFMA) + softmax + EPS + num/den partials ----------------
// block = (b, chunk of 256 n); 4 subchunks of 64 rows staged full (k+v) in LDS.
__global__ __launch_bounds__(256) void k45_attn(const unsigned short* __restrict__ kv,
                                                const float* __restrict__ qbuf,
                                                float* __restrict__ num_part,
                                                float* __restrict__ den_part) {
  __shared__ unsigned short kvs[64 * 256];   // 32KB, swizzled chunks
  __shared__ float att[16 * 68];             // [s][n] for one subchunk
  __shared__ float red4[4][16];
  const int t = threadIdx.x;
  const int lane = t & 63, w = t >> 6;
  const int b = blockIdx.x >> 4, chunk = blockIdx.x & (NCH_ - 1);

  // --- q as MFMA B-fragments, held in registers for the whole block ---
  int sqi = lane & 15; if (sqi > 10) sqi = 10;           // clamp (masked later)
  const float* qp = qbuf + ((size_t)b * S_ + sqi) * 128 + (lane >> 4) * 8;
  bf16x8 qf[4];
#pragma unroll
  for (int ks = 0; ks < 4; ks++) {
    float4 q0 = *(const float4*)(qp + ks * 32);
    float4 q1 = *(const float4*)(qp + ks * 32 + 4);
    uint4 uu;
    uu.x = pk2(q0.x, q0.y); uu.y = pk2(q0.z, q0.w);
    uu.z = pk2(q1.x, q1.y); uu.w = pk2(q1.z, q1.w);
    qf[ks] = __builtin_bit_cast(bf16x8, uu);
  }

  const int kk = t & 127, sh = t >> 7;
  const int s0 = sh ? 6 : 0, ns = sh ? 5 : 6;
  float acc[6] = {0, 0, 0, 0, 0, 0};
  float dden = 0.f;
  const bool dead = (lane & 15) >= 11;

  for (int sc = 0; sc < 4; sc++) {
    const long n0g = (long)b * N_ + chunk * 256 + sc * 64;
    __syncthreads();                        // kvs free for restage
    // --- stage 64 full kv rows (32KB), source-preswizzled ---
#pragma unroll
    for (int i = 0; i < 8; i++) {
      int o = i * 4096 + t * 16;
      int rr = o >> 9;                       // row 0..63
      int sl = (o >> 4) & 31;
      int c = sl ^ (rr & 7);
      gl16((const char*)kv + (n0g + rr) * 512 + c * 16,
           (char*)kvs + i * 4096 + w * 1024);
    }
    __syncthreads();                        // barrier drains vmcnt

    // --- phase A: logits via MFMA (wave w owns rows w*16..+16) ---
    f32x4 lg = {0.f, 0.f, 0.f, 0.f};
#pragma unroll
    for (int ks = 0; ks < 4; ks++) {
      int row = w * 16 + (lane & 15);
      int slot = (4 * ks + (lane >> 4)) ^ (row & 7);
      bf16x8 af = *(const bf16x8*)((const char*)kvs + row * 512 + (slot << 4));
      lg = __builtin_amdgcn_mfma_f32_16x16x32_bf16(af, qf[ks], lg, 0, 0, 0);
    }
    float l0 = dead ? -1e30f : lg[0] * SCALE_;
    float l1 = dead ? -1e30f : lg[1] * SCALE_;
    float l2 = dead ? -1e30f : lg[2] * SCALE_;
    float l3 = dead ? -1e30f : lg[3] * SCALE_;
    float m0 = l0, m1 = l1, m2 = l2, m3 = l3;
#pragma unroll
    for (int o = 1; o < 16; o <<= 1) {
      m0 = fmaxf(m0, __shfl_xor(m0, o)); m1 = fmaxf(m1, __shfl_xor(m1, o));
      m2 = fmaxf(m2, __shfl_xor(m2, o)); m3 = fmaxf(m3, __shfl_xor(m3, o));
    }
    float e0 = __expf(l0 - m0), e1 = __expf(l1 - m1);
    float e2 = __expf(l2 - m2), e3 = __expf(l3 - m3);
    float t0 = e0, t1 = e1, t2 = e2, t3 = e3;
#pragma unroll
    for (int o = 1; o < 16; o <<= 1) {
      t0 += __shfl_xor(t0, o); t1 += __shfl_xor(t1, o);
      t2 += __shfl_xor(t2, o); t3 += __shfl_xor(t3, o);
    }
    float a0 = e0 / t0 + EPS_, a1 = e1 / t1 + EPS_;
    float a2 = e2 / t2 + EPS_, a3 = e3 / t3 + EPS_;
    {
      int sidx = lane & 15;
      int nb = w * 16 + (lane >> 4) * 4;
      att[sidx * 68 + nb + 0] = a0;
      att[sidx * 68 + nb + 1] = a1;
      att[sidx * 68 + nb + 2] = a2;
      att[sidx * 68 + nb + 3] = a3;
    }
    float dsub = a0 + a1 + a2 + a3;
    dsub += __shfl_xor(dsub, 16);
    dsub += __shfl_xor(dsub, 32);
    dden += dsub;
    __syncthreads();                        // att ready (kvs v-half still valid)

    // --- phase B: acc[s] += att[s][nn] * v[nn][kk] over the 64 rows ---
#pragma unroll 2
    for (int nn = 0; nn < 64; nn++) {
      float v = b2f(*(const unsigned short*)((const char*)kvs + nn * 512 +
                    ((16 + ((kk >> 3) ^ (nn & 7))) << 4) + ((kk & 7) << 1)));
#pragma unroll
      for (int j = 0; j < 6; j++)
        if (j < ns) acc[j] += att[(s0 + j) * 68 + nn] * v;
    }
  }

  if (lane < 16) red4[w][lane] = dden;
  __syncthreads();
  if (t < S_) {
    float d = red4[0][t] + red4[1][t] + red4[2][t] + red4[3][t];
    den_part[((size_t)b * NCH_ + chunk) * S_ + t] = d;
  }
  for (int j = 0; j < ns; j++)
    num_part[(((size_t)b * NCH_ + chunk) * S_ + s0 + j) * 128 + kk] = acc[j];
}

// ---------------- K6: finalize updates, GRU, MLP -> slots ----------------
__global__ __launch_bounds__(128) void k6_final(const float* __restrict__ num_part,
                                                const float* __restrict__ den_part,
                                                float* __restrict__ slots,
                                                const float* __restrict__ w_ih,
                                                const float* __restrict__ w_hh,
                                                const float* __restrict__ b_ih,
                                                const float* __restrict__ b_hh,
                                                const float* __restrict__ lmw,
                                                const float* __restrict__ lmb,
                                                const float* __restrict__ w1,
                                                const float* __restrict__ bb1,
                                                const float* __restrict__ w2,
                                                const float* __restrict__ bb2) {
  int bs = blockIdx.x;
  int b = bs / S_, s = bs % S_;
  int j = threadIdx.x;
  __shared__ float u[128], h[128], m[128], hid[256];
  __shared__ float red2[2];

  float den = 0.f;
#pragma unroll
  for (int c = 0; c < NCH_; c++) den += den_part[((size_t)b * NCH_ + c) * S_ + s];
  float uj = 0.f;
#pragma unroll
  for (int c = 0; c < NCH_; c++) uj += num_part[(((size_t)b * NCH_ + c) * S_ + s) * 128 + j];
  uj /= den;
  float hj = slots[((size_t)b * S_ + s) * 128 + j];
  u[j] = uj; h[j] = hj;
  __syncthreads();

  float gir = b_ih[j], giz = b_ih[128 + j], gin = b_ih[256 + j];
  float ghr = b_hh[j], ghz = b_hh[128 + j], ghn = b_hh[256 + j];
#pragma unroll 4
  for (int kk = 0; kk < 128; kk++) {
    float uk = u[kk], hk = h[kk];
    gir += w_ih[j * 128 + kk] * uk;
    giz += w_ih[(128 + j) * 128 + kk] * uk;
    gin += w_ih[(256 + j) * 128 + kk] * uk;
    ghr += w_hh[j * 128 + kk] * hk;
    ghz += w_hh[(128 + j) * 128 + kk] * hk;
    ghn += w_hh[(256 + j) * 128 + kk] * hk;
  }
  float r = 1.f / (1.f + __expf(-(gir + ghr)));
  float z = 1.f / (1.f + __expf(-(giz + ghz)));
  float nn = tanhf(gin + r * ghn);
  float sj = (1.f - z) * nn + z * hj;

  float sum = redsum128(sj, red2);
  float sq  = redsum128(sj * sj, red2);
  float mean = sum * (1.f / 128.f);
  float var  = sq * (1.f / 128.f) - mean * mean;
  float mj = (sj - mean) * rsqrtf(var + LN_EPS_) * lmw[j] + lmb[j];
  m[j] = mj;
  __syncthreads();

  for (int hh = j; hh < 256; hh += 128) {
    float a = bb1[hh];
#pragma unroll 4
    for (int kk = 0; kk < 128; kk++) a += w1[hh * 128 + kk] * m[kk];
    hid[hh] = fmaxf(a, 0.f);
  }
  __syncthreads();

  float o = sj + bb2[j];
#pragma unroll 4
  for (int hh = 0; hh < 256; hh++) o += w2[j * 256 + hh] * hid[hh];
  slots[((size_t)b * S_ + s) * 128 + j] = o;
}

// ---------------- copy out ----------------
__global__ __launch_bounds__(256) void k_copy(const float* __restrict__ slots,
                                              float* __restrict__ out) {
  int i = blockIdx.x * 256 + threadIdx.x;
  out[i] = slots[i];
}

extern "C" void kernel_launch(void* const* d_in, const int* in_sizes, int n_in,
                              void* d_out, int out_size, void* d_ws, size_t ws_size,
                              hipStream_t stream) {
  (void)in_sizes; (void)n_in; (void)out_size; (void)ws_size;
  const float* inputs     = (const float*)d_in[0];
  const float* slots_init = (const float*)d_in[1];
  const float* slots_mu   = (const float*)d_in[2];
  const float* slots_ls   = (const float*)d_in[3];
  const float* ln_in_w    = (const float*)d_in[4];
  const float* ln_in_b    = (const float*)d_in[5];
  const float* ln_slot_w  = (const float*)d_in[6];
  const float* ln_slot_b  = (const float*)d_in[7];
  const float* ln_mlp_w   = (const float*)d_in[8];
  const float* ln_mlp_b   = (const float*)d_in[9];
  const float* Wq         = (const float*)d_in[10];
  const float* Wk         = (const float*)d_in[11];
  const float* Wv         = (const float*)d_in[12];
  const float* w_ih       = (const float*)d_in[13];
  const float* w_hh       = (const float*)d_in[14];
  const float* b_ih       = (const float*)d_in[15];
  const float* b_hh       = (const float*)d_in[16];
  const float* mlp_w1     = (const float*)d_in[17];
  const float* mlp_b1     = (const float*)d_in[18];
  const float* mlp_w2     = (const float*)d_in[19];
  const float* mlp_b2     = (const float*)d_in[20];

  uintptr_t p = (uintptr_t)d_ws;
  auto carve = [&](size_t bytes) -> void* {
    void* r = (void*)p;
    p += (bytes + 255) & ~(size_t)255;
    return r;
  };
  unsigned short* kv = (unsigned short*)carve((size_t)B_ * N_ * 2 * K_ * 2);
  unsigned short* W2 = (unsigned short*)carve((size_t)256 * 256 * 2);
  float* qbuf     = (float*)carve((size_t)B_ * S_ * K_ * 4);
  float* slots    = (float*)carve((size_t)B_ * S_ * K_ * 4);
  float* den_part = (float*)carve((size_t)B_ * NCH_ * S_ * 4);
  float* num_part = (float*)carve((size_t)B_ * NCH_ * S_ * K_ * 4);

  k0_wcast<<<256, 256, 0, stream>>>(Wk, Wv, W2);
  k_init<<<(B_ * S_ * K_) / 256, 256, 0, stream>>>(slots_init, slots_mu, slots_ls, slots);
  k12_lngemm<<<(B_ * N_) / 64, 256, 0, stream>>>(inputs, ln_in_w, ln_in_b, W2, kv);

  for (int it = 0; it < ITERS_; ++it) {
    k3_q<<<B_ * S_, 128, 0, stream>>>(slots, ln_slot_w, ln_slot_b, Wq, qbuf);
    k45_attn<<<B_ * NCH_, 256, 0, stream>>>(kv, qbuf, num_part, den_part);
    k6_final<<<B_ * S_, 128, 0, stream>>>(num_part, den_part, slots,
                                          w_ih, w_hh, b_ih, b_hh,
                                          ln_mlp_w, ln_mlp_b,
                                          mlp_w1, mlp_b1, mlp_w2, mlp_b2);
  }
  k_copy<<<(B_ * S_ * K_) / 256, 256, 0, stream>>>(slots, (float*)d_out);
}

// Round 3
// 402.516 us; speedup vs baseline: 3.2942x; 1.4538x over previous
//
#include <hip/hip_runtime.h>
#include <hip/hip_bf16.h>
#include <cstdint>
#include <cstddef>

#define B_ 64
#define N_ 4096
#define D_ 256
#define S_ 11
#define K_ 128
#define H_ 256
#define ITERS_ 3
#define EPS_ 1e-6f
#define LN_EPS_ 1e-5f
#define SCALE_ 0.08838834764831845f   // 128^-0.5
#define NCH_ 16                        // n-chunks per batch in k45

typedef __bf16 bf16x8 __attribute__((ext_vector_type(8)));
typedef float  f32x4  __attribute__((ext_vector_type(4)));

__device__ __forceinline__ unsigned short f2bu(float f) {
  unsigned int u = __builtin_bit_cast(unsigned int, f);
  u += 0x7fffu + ((u >> 16) & 1u);   // round-to-nearest-even
  return (unsigned short)(u >> 16);
}
__device__ __forceinline__ unsigned int pk2(float a, float b) {
  return (unsigned int)f2bu(a) | ((unsigned int)f2bu(b) << 16);
}

// ---------------- KPREP: W2 cast + slots init + weight transposes ----------------
__global__ __launch_bounds__(256) void kprep(const float* __restrict__ Wk,
                                             const float* __restrict__ Wv,
                                             unsigned short* __restrict__ W2,
                                             const float* __restrict__ si,
                                             const float* __restrict__ mu,
                                             const float* __restrict__ ls,
                                             float* __restrict__ slots,
                                             const float* __restrict__ w_ih,
                                             const float* __restrict__ w_hh,
                                             float* __restrict__ wTih,
                                             float* __restrict__ wThh,
                                             const float* __restrict__ w1,
                                             float* __restrict__ w1T,
                                             const float* __restrict__ w2,
                                             float* __restrict__ w2T,
                                             const float* __restrict__ Wq,
                                             float* __restrict__ WqT) {
  int bid = blockIdx.x, t = threadIdx.x;
  if (bid < 256) {                       // W2 cast: 65536
    int i = bid * 256 + t;
    int j = i >> 8, d = i & 255;
    float v = (j < 128) ? Wk[j * 256 + d] : Wv[(j - 128) * 256 + d];
    W2[i] = f2bu(v);
  } else if (bid < 608) {                // slots init: 90112
    int i = (bid - 256) * 256 + t;
    int k = i & 127;
    slots[i] = mu[k] + __expf(ls[k]) * si[i];
  } else if (bid < 800) {                // w_ih^T: 49152
    int i = (bid - 608) * 256 + t;
    int r = i >> 7, c = i & 127;
    wTih[c * 384 + r] = w_ih[i];
  } else if (bid < 992) {                // w_hh^T: 49152
    int i = (bid - 800) * 256 + t;
    int r = i >> 7, c = i & 127;
    wThh[c * 384 + r] = w_hh[i];
  } else if (bid < 1120) {               // mlp_w1^T: 32768  [256][128]->[128][256]
    int i = (bid - 992) * 256 + t;
    int r = i >> 7, c = i & 127;
    w1T[c * 256 + r] = w1[i];
  } else if (bid < 1248) {               // mlp_w2^T: 32768  [128][256]->[256][128]
    int i = (bid - 1120) * 256 + t;
    int r = i >> 8, c = i & 255;
    w2T[c * 128 + r] = w2[i];
  } else {                               // Wq^T: 16384
    int i = (bid - 1248) * 256 + t;
    int r = i >> 7, c = i & 127;
    WqT[c * 128 + r] = Wq[i];
  }
}

// ---------------- K12: fused LN(inputs) + GEMM -> k_arr + v_t ----------------
// BM=64, BN=256, 256 thr = 4 waves (N-split 64 each). B-frags straight from
// global (L2-resident W2), 2-deep prefetch, NO barriers in K-loop.
__global__ __launch_bounds__(256) void k12_lngemm(const float* __restrict__ x,
                                                  const float* __restrict__ lnw,
                                                  const float* __restrict__ lnb,
                                                  const unsigned short* __restrict__ W2,
                                                  unsigned short* __restrict__ k_arr,
                                                  unsigned short* __restrict__ v_t) {
  __shared__ char smem[36864];
  unsigned short* As = (unsigned short*)smem;     // [64][256] bf16 swizzled (32KB)
  const int t = threadIdx.x;
  const int lane = t & 63, w = t >> 6;
  const int bm = blockIdx.x;
  const long rowg0 = (long)bm * 64;

  // ---- LN stage: row r = t>>2, quad kq = t&3 owns chunks kq+4j ----
  {
    const int r = t >> 2, kq = t & 3;
    const float* xrow = x + (rowg0 + r) * 256;
    float4 xa[16];
    float s = 0.f, sq = 0.f;
#pragma unroll
    for (int j = 0; j < 8; j++) {
      int cb = kq + 4 * j;
      xa[2 * j]     = *(const float4*)(xrow + cb * 8);
      xa[2 * j + 1] = *(const float4*)(xrow + cb * 8 + 4);
      float4 a = xa[2 * j], b = xa[2 * j + 1];
      s  += a.x + a.y + a.z + a.w + b.x + b.y + b.z + b.w;
      sq += a.x * a.x + a.y * a.y + a.z * a.z + a.w * a.w
          + b.x * b.x + b.y * b.y + b.z * b.z + b.w * b.w;
    }
    s  += __shfl_xor(s, 1);  s  += __shfl_xor(s, 2);
    sq += __shfl_xor(sq, 1); sq += __shfl_xor(sq, 2);
    float mean = s * (1.f / 256.f);
    float var  = sq * (1.f / 256.f) - mean * mean;
    float rstd = rsqrtf(var + LN_EPS_);
#pragma unroll
    for (int j = 0; j < 8; j++) {
      int cb = kq + 4 * j;
      float4 w0 = *(const float4*)(lnw + cb * 8);
      float4 w1v = *(const float4*)(lnw + cb * 8 + 4);
      float4 b0 = *(const float4*)(lnb + cb * 8);
      float4 b1v = *(const float4*)(lnb + cb * 8 + 4);
      float4 a = xa[2 * j], b = xa[2 * j + 1];
      uint4 u;
      u.x = pk2((a.x - mean) * rstd * w0.x + b0.x, (a.y - mean) * rstd * w0.y + b0.y);
      u.y = pk2((a.z - mean) * rstd * w0.z + b0.z, (a.w - mean) * rstd * w0.w + b0.w);
      u.z = pk2((b.x - mean) * rstd * w1v.x + b1v.x, (b.y - mean) * rstd * w1v.y + b1v.y);
      u.w = pk2((b.z - mean) * rstd * w1v.z + b1v.z, (b.w - mean) * rstd * w1v.w + b1v.w);
      *(uint4*)(smem + r * 512 + ((cb ^ (r & 7)) << 4)) = u;
    }
  }
  __syncthreads();   // As ready; read-only below

  f32x4 acc[4][4] = {};
  bf16x8 bA[8], bB[8];

  auto loadB = [&](int kt, bf16x8* dst) {
#pragma unroll
    for (int kk = 0; kk < 2; kk++)
#pragma unroll
      for (int j = 0; j < 4; j++) {
        int rowb = w * 64 + j * 16 + (lane & 15);
        dst[kk * 4 + j] = *(const bf16x8*)(W2 + rowb * 256 + kt * 64 + kk * 32 + (lane >> 4) * 8);
      }
  };
  auto compute = [&](int kt, const bf16x8* bf) {
#pragma unroll
    for (int kk = 0; kk < 2; kk++) {
      bf16x8 af[4];
#pragma unroll
      for (int i = 0; i < 4; i++) {
        int row = i * 16 + (lane & 15);
        int slot = (kt * 8 + kk * 4 + (lane >> 4)) ^ (lane & 7);
        af[i] = *(const bf16x8*)(smem + row * 512 + (slot << 4));
      }
#pragma unroll
      for (int i = 0; i < 4; i++)
#pragma unroll
        for (int j = 0; j < 4; j++)
          acc[i][j] = __builtin_amdgcn_mfma_f32_16x16x32_bf16(af[i], bf[kk * 4 + j], acc[i][j], 0, 0, 0);
    }
  };

  loadB(0, bA);
  loadB(1, bB); compute(0, bA);
  loadB(2, bA); compute(1, bB);
  loadB(3, bB); compute(2, bA);
  compute(3, bB);

  // ---- epilogue: waves 0,1 stage k-half; waves 2,3 stage v-half transposed ----
  __syncthreads();   // done reading As
  unsigned short* ks_st = (unsigned short*)smem;            // [64][128] swizzled 16KB
  char* vs_st = smem + 16384;                               // [128] rows of 144B
  if (w < 2) {
#pragma unroll
    for (int i = 0; i < 4; i++)
#pragma unroll
      for (int j = 0; j < 4; j++)
#pragma unroll
        for (int rr = 0; rr < 4; rr++) {
          int row = i * 16 + (lane >> 4) * 4 + rr;
          int col = w * 64 + j * 16 + (lane & 15);
          *(unsigned short*)((char*)ks_st + row * 256 +
                             (((col >> 3) ^ (row & 7)) << 4) + ((col & 7) << 1)) =
              f2bu(acc[i][j][rr]);
        }
  } else {
#pragma unroll
    for (int i = 0; i < 4; i++)
#pragma unroll
      for (int j = 0; j < 4; j++) {
        int k = (w - 2) * 64 + j * 16 + (lane & 15);
        int n = i * 16 + (lane >> 4) * 4;
        uint2 pk;
        pk.x = pk2(acc[i][j][0], acc[i][j][1]);
        pk.y = pk2(acc[i][j][2], acc[i][j][3]);
        *(uint2*)(vs_st + k * 144 + n * 2) = pk;
      }
  }
  __syncthreads();
  const long bb  = rowg0 >> 12;
  const int  nt0 = (int)(rowg0 & 4095);
#pragma unroll
  for (int i = 0; i < 4; i++) {         // k_arr: 16KB
    int o = i * 4096 + t * 16;
    int row = o >> 8, ch = (o >> 4) & 15;
    uint4 val = *(const uint4*)((const char*)ks_st + row * 256 + ((ch ^ (row & 7)) << 4));
    *(uint4*)(k_arr + (bb * 4096 + nt0 + row) * 128 + ch * 8) = val;
  }
#pragma unroll
  for (int i = 0; i < 4; i++) {         // v_t: 16KB
    int o = i * 4096 + t * 16;
    int kr = o >> 7, ch = (o >> 4) & 7;
    uint4 val = *(const uint4*)(vs_st + kr * 144 + ch * 16);
    *(uint4*)(v_t + (bb * 128 + kr) * 4096 + nt0 + ch * 8) = val;
  }
}

// ---------------- reduce helper: sum over 128 threads ----------------
__device__ __forceinline__ float redsum128(float v, float* red2) {
#pragma unroll
  for (int o = 1; o < 64; o <<= 1) v += __shfl_xor(v, o);
  __syncthreads();
  if ((threadIdx.x & 63) == 0) red2[threadIdx.x >> 6] = v;
  __syncthreads();
  return red2[0] + red2[1];
}

// ---------------- K3: sn = LN(slots); q = sn * Wq^T  (WqT coalesced) ----------------
__global__ __launch_bounds__(128) void k3_q(const float* __restrict__ slots,
                                            const float* __restrict__ lw,
                                            const float* __restrict__ lb,
                                            const float* __restrict__ WqT,
                                            float* __restrict__ q) {
  int bs = blockIdx.x;
  int j = threadIdx.x;
  __shared__ float sn[128];
  __shared__ float red2[2];
  float x = slots[(size_t)bs * 128 + j];
  float sum = redsum128(x, red2);
  float sq  = redsum128(x * x, red2);
  float mean = sum * (1.f / 128.f);
  float var  = sq * (1.f / 128.f) - mean * mean;
  float v = (x - mean) * rsqrtf(var + LN_EPS_) * lw[j] + lb[j];
  sn[j] = v;
  __syncthreads();
  float acc = 0.f;
#pragma unroll 8
  for (int kk = 0; kk < 128; kk++) acc += sn[kk] * WqT[kk * 128 + j];
  q[(size_t)bs * 128 + j] = acc;
}

// ---------------- K45: logits(MFMA) + softmax + updates(MFMA) ----------------
// block = (b, 256-row n-chunk); k from k_arr direct, v from v_t direct; att in LDS bf16.
__global__ __launch_bounds__(256) void k45_attn(const unsigned short* __restrict__ k_arr,
                                                const unsigned short* __restrict__ v_t,
                                                const float* __restrict__ qbuf,
                                                float* __restrict__ num_part,
                                                float* __restrict__ den_part) {
  __shared__ unsigned short att[16 * 264];   // stride 264 bf16 (528B); 8.25KB
  __shared__ float redd[4][16];
  const int t = threadIdx.x;
  const int lane = t & 63, w = t >> 6;
  const int b = blockIdx.x >> 4, chunk = blockIdx.x & (NCH_ - 1);
  const int n0 = chunk * 256;

  // q as MFMA B-fragments (col = s = lane&15, 8 consecutive k at (lane>>4)*8)
  int sqi = lane & 15; if (sqi > 10) sqi = 10;
  const float* qp = qbuf + ((size_t)b * S_ + sqi) * 128 + (lane >> 4) * 8;
  bf16x8 qf[4];
#pragma unroll
  for (int ks = 0; ks < 4; ks++) {
    float4 q0 = *(const float4*)(qp + ks * 32);
    float4 q1 = *(const float4*)(qp + ks * 32 + 4);
    uint4 uu;
    uu.x = pk2(q0.x, q0.y); uu.y = pk2(q0.z, q0.w);
    uu.z = pk2(q1.x, q1.y); uu.w = pk2(q1.z, q1.w);
    qf[ks] = __builtin_bit_cast(bf16x8, uu);
  }
  const bool dead = (lane & 15) >= 11;
  const unsigned short* kbase = k_arr + ((size_t)b * N_ + n0) * 128;
  float dden = 0.f;

  // ---- phase A: logits + softmax -> att LDS (bf16) ----
#pragma unroll
  for (int u = 0; u < 4; u++) {
    int nloc = w * 64 + u * 16 + (lane & 15);
    const unsigned short* kr = kbase + (size_t)nloc * 128 + (lane >> 4) * 8;
    f32x4 lg = {0.f, 0.f, 0.f, 0.f};
#pragma unroll
    for (int ks = 0; ks < 4; ks++) {
      bf16x8 af = *(const bf16x8*)(kr + ks * 32);
      lg = __builtin_amdgcn_mfma_f32_16x16x32_bf16(af, qf[ks], lg, 0, 0, 0);
    }
    float l0 = dead ? -1e30f : lg[0] * SCALE_;
    float l1 = dead ? -1e30f : lg[1] * SCALE_;
    float l2 = dead ? -1e30f : lg[2] * SCALE_;
    float l3 = dead ? -1e30f : lg[3] * SCALE_;
    float m0 = l0, m1 = l1, m2 = l2, m3 = l3;
#pragma unroll
    for (int o = 1; o < 16; o <<= 1) {
      m0 = fmaxf(m0, __shfl_xor(m0, o)); m1 = fmaxf(m1, __shfl_xor(m1, o));
      m2 = fmaxf(m2, __shfl_xor(m2, o)); m3 = fmaxf(m3, __shfl_xor(m3, o));
    }
    float e0 = __expf(l0 - m0), e1 = __expf(l1 - m1);
    float e2 = __expf(l2 - m2), e3 = __expf(l3 - m3);
    float t0 = e0, t1 = e1, t2 = e2, t3 = e3;
#pragma unroll
    for (int o = 1; o < 16; o <<= 1) {
      t0 += __shfl_xor(t0, o); t1 += __shfl_xor(t1, o);
      t2 += __shfl_xor(t2, o); t3 += __shfl_xor(t3, o);
    }
    float a0 = e0 / t0 + EPS_, a1 = e1 / t1 + EPS_;
    float a2 = e2 / t2 + EPS_, a3 = e3 / t3 + EPS_;
    dden += a0 + a1 + a2 + a3;
    uint2 pk;
    pk.x = pk2(a0, a1); pk.y = pk2(a2, a3);
    int s = lane & 15;
    int nn = w * 64 + u * 16 + (lane >> 4) * 4;
    *(uint2*)((char*)att + s * 528 + nn * 2) = pk;
  }
  dden += __shfl_xor(dden, 16);
  dden += __shfl_xor(dden, 32);
  if (lane < 16) redd[w][lane] = dden;
  __syncthreads();
  if (t < S_)
    den_part[((size_t)b * NCH_ + chunk) * S_ + t] =
        redd[0][t] + redd[1][t] + redd[2][t] + redd[3][t];

  // ---- phase B: updates[s][k] += att[s][n] * v_t[k][n] via MFMA ----
  f32x4 acc[2] = {};
  const unsigned short* vtb = v_t + (size_t)b * 128 * N_ + n0;
#pragma unroll
  for (int ks = 0; ks < 8; ks++) {
    bf16x8 pa = *(const bf16x8*)((const char*)att + (lane & 15) * 528 +
                                 (ks * 32 + (lane >> 4) * 8) * 2);
#pragma unroll
    for (int j = 0; j < 2; j++) {
      int k = w * 32 + j * 16 + (lane & 15);
      bf16x8 vb = *(const bf16x8*)(vtb + (size_t)k * N_ + ks * 32 + (lane >> 4) * 8);
      acc[j] = __builtin_amdgcn_mfma_f32_16x16x32_bf16(pa, vb, acc[j], 0, 0, 0);
    }
  }
#pragma unroll
  for (int j = 0; j < 2; j++)
#pragma unroll
    for (int r = 0; r < 4; r++) {
      int s = (lane >> 4) * 4 + r;
      if (s < S_) {
        int k = w * 32 + j * 16 + (lane & 15);
        num_part[(((size_t)b * NCH_ + chunk) * S_ + s) * 128 + k] = acc[j][r];
      }
    }
}

// ---------------- K6: finalize updates, GRU, MLP -> slots (transposed weights) ----------------
__global__ __launch_bounds__(128) void k6_final(const float* __restrict__ num_part,
                                                const float* __restrict__ den_part,
                                                float* __restrict__ slots,
                                                const float* __restrict__ wTih,
                                                const float* __restrict__ wThh,
                                                const float* __restrict__ b_ih,
                                                const float* __restrict__ b_hh,
                                                const float* __restrict__ lmw,
                                                const float* __restrict__ lmb,
                                                const float* __restrict__ w1T,
                                                const float* __restrict__ bb1,
                                                const float* __restrict__ w2T,
                                                const float* __restrict__ bb2) {
  int bs = blockIdx.x;
  int b = bs / S_, s = bs % S_;
  int j = threadIdx.x;
  __shared__ float u[128], h[128], m[128], hid[256];
  __shared__ float red2[2];

  float den = 0.f;
#pragma unroll
  for (int c = 0; c < NCH_; c++) den += den_part[((size_t)b * NCH_ + c) * S_ + s];
  float uj = 0.f;
#pragma unroll
  for (int c = 0; c < NCH_; c++) uj += num_part[(((size_t)b * NCH_ + c) * S_ + s) * 128 + j];
  uj /= den;
  float hj = slots[((size_t)b * S_ + s) * 128 + j];
  u[j] = uj; h[j] = hj;
  __syncthreads();

  float gir = b_ih[j], giz = b_ih[128 + j], gin = b_ih[256 + j];
  float ghr = b_hh[j], ghz = b_hh[128 + j], ghn = b_hh[256 + j];
#pragma unroll 4
  for (int kk = 0; kk < 128; kk++) {
    float uk = u[kk], hk = h[kk];
    const float* wi = wTih + kk * 384;
    const float* wh = wThh + kk * 384;
    gir += wi[j] * uk;
    giz += wi[128 + j] * uk;
    gin += wi[256 + j] * uk;
    ghr += wh[j] * hk;
    ghz += wh[128 + j] * hk;
    ghn += wh[256 + j] * hk;
  }
  float r = 1.f / (1.f + __expf(-(gir + ghr)));
  float z = 1.f / (1.f + __expf(-(giz + ghz)));
  float nn = tanhf(gin + r * ghn);
  float sj = (1.f - z) * nn + z * hj;

  float sum = redsum128(sj, red2);
  float sq  = redsum128(sj * sj, red2);
  float mean = sum * (1.f / 128.f);
  float var  = sq * (1.f / 128.f) - mean * mean;
  float mj = (sj - mean) * rsqrtf(var + LN_EPS_) * lmw[j] + lmb[j];
  m[j] = mj;
  __syncthreads();

  for (int hh = j; hh < 256; hh += 128) {
    float a = bb1[hh];
#pragma unroll 4
    for (int kk = 0; kk < 128; kk++) a += w1T[kk * 256 + hh] * m[kk];
    hid[hh] = fmaxf(a, 0.f);
  }
  __syncthreads();

  float o = sj + bb2[j];
#pragma unroll 4
  for (int hh = 0; hh < 256; hh++) o += w2T[hh * 128 + j] * hid[hh];
  slots[((size_t)b * S_ + s) * 128 + j] = o;
}

// ---------------- copy out ----------------
__global__ __launch_bounds__(256) void k_copy(const float* __restrict__ slots,
                                              float* __restrict__ out) {
  int i = blockIdx.x * 256 + threadIdx.x;
  out[i] = slots[i];
}

extern "C" void kernel_launch(void* const* d_in, const int* in_sizes, int n_in,
                              void* d_out, int out_size, void* d_ws, size_t ws_size,
                              hipStream_t stream) {
  (void)in_sizes; (void)n_in; (void)out_size; (void)ws_size;
  const float* inputs     = (const float*)d_in[0];
  const float* slots_init = (const float*)d_in[1];
  const float* slots_mu   = (const float*)d_in[2];
  const float* slots_ls   = (const float*)d_in[3];
  const float* ln_in_w    = (const float*)d_in[4];
  const float* ln_in_b    = (const float*)d_in[5];
  const float* ln_slot_w  = (const float*)d_in[6];
  const float* ln_slot_b  = (const float*)d_in[7];
  const float* ln_mlp_w   = (const float*)d_in[8];
  const float* ln_mlp_b   = (const float*)d_in[9];
  const float* Wq         = (const float*)d_in[10];
  const float* Wk         = (const float*)d_in[11];
  const float* Wv         = (const float*)d_in[12];
  const float* w_ih       = (const float*)d_in[13];
  const float* w_hh       = (const float*)d_in[14];
  const float* b_ih       = (const float*)d_in[15];
  const float* b_hh       = (const float*)d_in[16];
  const float* mlp_w1     = (const float*)d_in[17];
  const float* mlp_b1     = (const float*)d_in[18];
  const float* mlp_w2     = (const float*)d_in[19];
  const float* mlp_b2     = (const float*)d_in[20];

  uintptr_t p = (uintptr_t)d_ws;
  auto carve = [&](size_t bytes) -> void* {
    void* r = (void*)p;
    p += (bytes + 255) & ~(size_t)255;
    return r;
  };
  unsigned short* k_arr = (unsigned short*)carve((size_t)B_ * N_ * K_ * 2);
  unsigned short* v_t   = (unsigned short*)carve((size_t)B_ * K_ * N_ * 2);
  unsigned short* W2    = (unsigned short*)carve((size_t)256 * 256 * 2);
  float* wTih  = (float*)carve((size_t)128 * 384 * 4);
  float* wThh  = (float*)carve((size_t)128 * 384 * 4);
  float* w1T   = (float*)carve((size_t)128 * 256 * 4);
  float* w2T   = (float*)carve((size_t)256 * 128 * 4);
  float* WqT   = (float*)carve((size_t)128 * 128 * 4);
  float* qbuf     = (float*)carve((size_t)B_ * S_ * K_ * 4);
  float* slots    = (float*)carve((size_t)B_ * S_ * K_ * 4);
  float* den_part = (float*)carve((size_t)B_ * NCH_ * S_ * 4);
  float* num_part = (float*)carve((size_t)B_ * NCH_ * S_ * K_ * 4);

  kprep<<<1312, 256, 0, stream>>>(Wk, Wv, W2, slots_init, slots_mu, slots_ls, slots,
                                  w_ih, w_hh, wTih, wThh, mlp_w1, w1T, mlp_w2, w2T,
                                  Wq, WqT);
  k12_lngemm<<<(B_ * N_) / 64, 256, 0, stream>>>(inputs, ln_in_w, ln_in_b, W2, k_arr, v_t);

  for (int it = 0; it < ITERS_; ++it) {
    k3_q<<<B_ * S_, 128, 0, stream>>>(slots, ln_slot_w, ln_slot_b, WqT, qbuf);
    k45_attn<<<B_ * NCH_, 256, 0, stream>>>(k_arr, v_t, qbuf, num_part, den_part);
    k6_final<<<B_ * S_, 128, 0, stream>>>(num_part, den_part, slots,
                                          wTih, wThh, b_ih, b_hh,
                                          ln_mlp_w, ln_mlp_b,
                                          w1T, mlp_b1, w2T, mlp_b2);
  }
  k_copy<<<(B_ * S_ * K_) / 256, 256, 0, stream>>>(slots, (float*)d_out);
}

// Round 4
// 288.517 us; speedup vs baseline: 4.5958x; 1.3951x over previous
//
#include <hip/hip_runtime.h>
#include <hip/hip_bf16.h>
#include <cstdint>
#include <cstddef>

#define B_ 64
#define N_ 4096
#define D_ 256
#define S_ 11
#define K_ 128
#define H_ 256
#define ITERS_ 3
#define EPS_ 1e-6f
#define LN_EPS_ 1e-5f
#define SCALE_ 0.08838834764831845f   // 128^-0.5
#define NCH_ 16                        // n-chunks per batch in k45

typedef __bf16 bf16x8 __attribute__((ext_vector_type(8)));
typedef float  f32x4  __attribute__((ext_vector_type(4)));

__device__ __forceinline__ unsigned short f2bu(float f) {
  unsigned int u = __builtin_bit_cast(unsigned int, f);
  u += 0x7fffu + ((u >> 16) & 1u);   // round-to-nearest-even
  return (unsigned short)(u >> 16);
}
__device__ __forceinline__ unsigned int pk2(float a, float b) {
  return (unsigned int)f2bu(a) | ((unsigned int)f2bu(b) << 16);
}

// ---------------- KPREP: W2 fragment-pack + slots init + weight transposes ----------------
// W2pk layout (bf16, 16B chunks): chunk f -> lane=f&63, j=(f>>6)&3, kk=(f>>8)&1,
// kt=(f>>9)&3, w=f>>11; element = W[row=w*64+j*16+(lane&15)][kt*64+kk*32+(lane>>4)*8 .. +8]
__global__ __launch_bounds__(256) void kprep(const float* __restrict__ Wk,
                                             const float* __restrict__ Wv,
                                             unsigned short* __restrict__ W2pk,
                                             const float* __restrict__ si,
                                             const float* __restrict__ mu,
                                             const float* __restrict__ ls,
                                             float* __restrict__ slots,
                                             const float* __restrict__ w_ih,
                                             const float* __restrict__ w_hh,
                                             float* __restrict__ wTih,
                                             float* __restrict__ wThh,
                                             const float* __restrict__ w1,
                                             float* __restrict__ w1T,
                                             const float* __restrict__ w2,
                                             float* __restrict__ w2T,
                                             const float* __restrict__ Wq,
                                             float* __restrict__ WqT) {
  int bid = blockIdx.x, t = threadIdx.x;
  if (bid < 32) {                        // W2pk: 8192 x 16B chunks
    int f = bid * 256 + t;
    int ln_ = f & 63, jj = (f >> 6) & 3, kk2 = (f >> 8) & 1, kt = (f >> 9) & 3, ww = f >> 11;
    int row = ww * 64 + jj * 16 + (ln_ & 15);
    int col = kt * 64 + kk2 * 32 + (ln_ >> 4) * 8;
    const float* src = (row < 128) ? (Wk + row * 256 + col) : (Wv + (row - 128) * 256 + col);
    float4 a = *(const float4*)src;
    float4 b = *(const float4*)(src + 4);
    uint4 u;
    u.x = pk2(a.x, a.y); u.y = pk2(a.z, a.w); u.z = pk2(b.x, b.y); u.w = pk2(b.z, b.w);
    *(uint4*)(W2pk + (size_t)f * 8) = u;
  } else if (bid < 384) {                // slots init: 90112
    int i = (bid - 32) * 256 + t;
    int k = i & 127;
    slots[i] = mu[k] + __expf(ls[k]) * si[i];
  } else if (bid < 576) {                // w_ih^T: 49152
    int i = (bid - 384) * 256 + t;
    int r = i >> 7, c = i & 127;
    wTih[c * 384 + r] = w_ih[i];
  } else if (bid < 768) {                // w_hh^T: 49152
    int i = (bid - 576) * 256 + t;
    int r = i >> 7, c = i & 127;
    wThh[c * 384 + r] = w_hh[i];
  } else if (bid < 896) {                // mlp_w1^T: 32768  [256][128]->[128][256]
    int i = (bid - 768) * 256 + t;
    int r = i >> 7, c = i & 127;
    w1T[c * 256 + r] = w1[i];
  } else if (bid < 1024) {               // mlp_w2^T: 32768  [128][256]->[256][128]
    int i = (bid - 896) * 256 + t;
    int r = i >> 8, c = i & 255;
    w2T[c * 128 + r] = w2[i];
  } else {                               // Wq^T: 16384
    int i = (bid - 1024) * 256 + t;
    int r = i >> 7, c = i & 127;
    WqT[c * 128 + r] = Wq[i];
  }
}

// ---------------- K12: fused LN(inputs) + GEMM -> k_frag + v_frag ----------------
// BM=64, BN=256, 256 thr = 4 waves. All global loads wave-contiguous.
// k_frag: [(b*256+g)][ks 0..3][lane] 16B; element = k[n=g*16+(lane&15)][ks*32+(lane>>4)*8..+8]
// v_frag: [(b*128+nb)][kt 0..7][lane] 16B; element = v[n=nb*32+(lane>>4)*8+e][k=kt*16+(lane&15)]
__global__ __launch_bounds__(256) void k12_lngemm(const float* __restrict__ x,
                                                  const float* __restrict__ lnw,
                                                  const float* __restrict__ lnb,
                                                  const unsigned short* __restrict__ W2pk,
                                                  unsigned short* __restrict__ k_frag,
                                                  unsigned short* __restrict__ v_frag) {
  __shared__ char smem[36864];
  const int t = threadIdx.x;
  const int lane = t & 63, w = t >> 6;
  const long rowg0 = (long)blockIdx.x * 64;

  f32x4 acc[4][4] = {};
  bf16x8 bA[8], bB[8];
  auto loadB = [&](int kt, bf16x8* dst) {
#pragma unroll
    for (int kk = 0; kk < 2; kk++)
#pragma unroll
      for (int j = 0; j < 4; j++)
        dst[kk * 4 + j] =
            *(const bf16x8*)(W2pk + (size_t)(((((w * 4 + kt) * 2 + kk) * 4 + j) * 64) + lane) * 8);
  };

  loadB(0, bA);   // issue early; hides under LN

  // ---- LN: one wave per row, one coalesced float4 load per row ----
  {
    const float* xbase = x + (rowg0 + w * 16) * 256 + lane * 4;
    float4 xr[16];
#pragma unroll
    for (int rr = 0; rr < 16; rr++) xr[rr] = *(const float4*)(xbase + rr * 256);
    const float4 w4 = *(const float4*)(lnw + lane * 4);
    const float4 b4 = *(const float4*)(lnb + lane * 4);
#pragma unroll
    for (int rr = 0; rr < 16; rr++) {
      float4 xv = xr[rr];
      float s  = xv.x + xv.y + xv.z + xv.w;
      float sq = xv.x * xv.x + xv.y * xv.y + xv.z * xv.z + xv.w * xv.w;
#pragma unroll
      for (int o = 1; o < 64; o <<= 1) { s += __shfl_xor(s, o); sq += __shfl_xor(sq, o); }
      float mean = s * (1.f / 256.f);
      float var  = sq * (1.f / 256.f) - mean * mean;
      float rstd = rsqrtf(var + LN_EPS_);
      uint2 pk;
      pk.x = pk2((xv.x - mean) * rstd * w4.x + b4.x, (xv.y - mean) * rstd * w4.y + b4.y);
      pk.y = pk2((xv.z - mean) * rstd * w4.z + b4.z, (xv.w - mean) * rstd * w4.w + b4.w);
      int r = w * 16 + rr;
      int c = lane >> 1;                       // 16B chunk 0..31
      *(uint2*)(smem + r * 512 + ((c ^ (r & 7)) << 4) + ((lane & 1) << 3)) = pk;
    }
  }
  __syncthreads();   // As ready; read-only below

  auto compute = [&](int kt, const bf16x8* bf) {
#pragma unroll
    for (int kk = 0; kk < 2; kk++) {
      bf16x8 af[4];
#pragma unroll
      for (int i = 0; i < 4; i++) {
        int row = i * 16 + (lane & 15);
        int slot = (kt * 8 + kk * 4 + (lane >> 4)) ^ (lane & 7);
        af[i] = *(const bf16x8*)(smem + row * 512 + (slot << 4));
      }
#pragma unroll
      for (int i = 0; i < 4; i++)
#pragma unroll
        for (int j = 0; j < 4; j++)
          acc[i][j] = __builtin_amdgcn_mfma_f32_16x16x32_bf16(af[i], bf[kk * 4 + j], acc[i][j], 0, 0, 0);
    }
  };

  loadB(1, bB); compute(0, bA);
  loadB(2, bA); compute(1, bB);
  loadB(3, bB); compute(2, bA);
  compute(3, bB);

  // ---- epilogue: waves 0,1 stage k-half; waves 2,3 stage v-half transposed ----
  __syncthreads();   // done reading As
  char* ks_st = smem;                                       // [64][256B] swizzled, 16KB
  char* vs_st = smem + 16384;                               // [128] rows of 144B (=9x16B)
  if (w < 2) {
#pragma unroll
    for (int i = 0; i < 4; i++)
#pragma unroll
      for (int j = 0; j < 4; j++)
#pragma unroll
        for (int rr = 0; rr < 4; rr++) {
          int row = i * 16 + (lane >> 4) * 4 + rr;
          int col = w * 64 + j * 16 + (lane & 15);
          *(unsigned short*)(ks_st + row * 256 +
                             (((col >> 3) ^ (row & 7)) << 4) + ((col & 7) << 1)) =
              f2bu(acc[i][j][rr]);
        }
  } else {
#pragma unroll
    for (int i = 0; i < 4; i++)
#pragma unroll
      for (int j = 0; j < 4; j++) {
        int k = (w - 2) * 64 + j * 16 + (lane & 15);
        int n = i * 16 + (lane >> 4) * 4;
        uint2 pk;
        pk.x = pk2(acc[i][j][0], acc[i][j][1]);
        pk.y = pk2(acc[i][j][2], acc[i][j][3]);
        *(uint2*)(vs_st + k * 144 + n * 2) = pk;
      }
  }
  __syncthreads();
  // ---- k_frag store: 1024 chunks of 16B, fully coalesced ----
#pragma unroll
  for (int i = 0; i < 4; i++) {
    int f = i * 256 + t;
    int ln_ = f & 63, ks = (f >> 6) & 3, g = (f >> 8) & 3;
    int row = g * 16 + (ln_ & 15);
    int c = ks * 4 + (ln_ >> 4);
    uint4 val = *(const uint4*)(ks_st + row * 256 + ((c ^ (row & 7)) << 4));
    *(uint4*)(k_frag + (size_t)(((rowg0 >> 4) + g) * 4 + ks) * 512 + ln_ * 8) = val;
  }
  // ---- v_frag store: 1024 chunks of 16B, fully coalesced ----
#pragma unroll
  for (int i = 0; i < 4; i++) {
    int f = i * 256 + t;
    int ln_ = f & 63, kt_ = (f >> 6) & 7, nb = f >> 9;
    int k = kt_ * 16 + (ln_ & 15);
    uint4 val = *(const uint4*)(vs_st + k * 144 + nb * 64 + (ln_ >> 4) * 16);
    *(uint4*)(v_frag + (size_t)(((rowg0 >> 5) + nb) * 8 + kt_) * 512 + ln_ * 8) = val;
  }
}

// ---------------- reduce helper: sum over 128 threads ----------------
__device__ __forceinline__ float redsum128(float v, float* red2) {
#pragma unroll
  for (int o = 1; o < 64; o <<= 1) v += __shfl_xor(v, o);
  __syncthreads();
  if ((threadIdx.x & 63) == 0) red2[threadIdx.x >> 6] = v;
  __syncthreads();
  return red2[0] + red2[1];
}

// ---------------- K3: sn = LN(slots); q = sn * Wq^T ----------------
__global__ __launch_bounds__(128) void k3_q(const float* __restrict__ slots,
                                            const float* __restrict__ lw,
                                            const float* __restrict__ lb,
                                            const float* __restrict__ WqT,
                                            float* __restrict__ q) {
  int bs = blockIdx.x;
  int j = threadIdx.x;
  __shared__ float sn[128];
  __shared__ float red2[2];
  float x = slots[(size_t)bs * 128 + j];
  float sum = redsum128(x, red2);
  float sq  = redsum128(x * x, red2);
  float mean = sum * (1.f / 128.f);
  float var  = sq * (1.f / 128.f) - mean * mean;
  float v = (x - mean) * rsqrtf(var + LN_EPS_) * lw[j] + lb[j];
  sn[j] = v;
  __syncthreads();
  float acc = 0.f;
#pragma unroll 8
  for (int kk = 0; kk < 128; kk++) acc += sn[kk] * WqT[kk * 128 + j];
  q[(size_t)bs * 128 + j] = acc;
}

// ---------------- K45: logits(MFMA) + softmax + updates(MFMA), fragment inputs ----------------
__global__ __launch_bounds__(256) void k45_attn(const unsigned short* __restrict__ k_frag,
                                                const unsigned short* __restrict__ v_frag,
                                                const float* __restrict__ qbuf,
                                                float* __restrict__ num_part,
                                                float* __restrict__ den_part) {
  __shared__ unsigned short att[16 * 264];   // stride 264 bf16 (528B); 8.25KB
  __shared__ float redd[4][16];
  const int t = threadIdx.x;
  const int lane = t & 63, w = t >> 6;
  const int b = blockIdx.x >> 4, chunk = blockIdx.x & (NCH_ - 1);

  // q as MFMA B-fragments (col = s = lane&15)
  int sqi = lane & 15; if (sqi > 10) sqi = 10;
  const float* qp = qbuf + ((size_t)b * S_ + sqi) * 128 + (lane >> 4) * 8;
  bf16x8 qf[4];
#pragma unroll
  for (int ks = 0; ks < 4; ks++) {
    float4 q0 = *(const float4*)(qp + ks * 32);
    float4 q1 = *(const float4*)(qp + ks * 32 + 4);
    uint4 uu;
    uu.x = pk2(q0.x, q0.y); uu.y = pk2(q0.z, q0.w);
    uu.z = pk2(q1.x, q1.y); uu.w = pk2(q1.z, q1.w);
    qf[ks] = __builtin_bit_cast(bf16x8, uu);
  }
  const bool dead = (lane & 15) >= 11;
  float dden = 0.f;

  // ---- phase A: logits + softmax -> att LDS (bf16) ----
#pragma unroll
  for (int u = 0; u < 4; u++) {
    size_t g = (size_t)b * 256 + chunk * 16 + w * 4 + u;
    f32x4 lg = {0.f, 0.f, 0.f, 0.f};
#pragma unroll
    for (int ks = 0; ks < 4; ks++) {
      bf16x8 af = *(const bf16x8*)(k_frag + (g * 4 + ks) * 512 + lane * 8);
      lg = __builtin_amdgcn_mfma_f32_16x16x32_bf16(af, qf[ks], lg, 0, 0, 0);
    }
    float l0 = dead ? -1e30f : lg[0] * SCALE_;
    float l1 = dead ? -1e30f : lg[1] * SCALE_;
    float l2 = dead ? -1e30f : lg[2] * SCALE_;
    float l3 = dead ? -1e30f : lg[3] * SCALE_;
    float m0 = l0, m1 = l1, m2 = l2, m3 = l3;
#pragma unroll
    for (int o = 1; o < 16; o <<= 1) {
      m0 = fmaxf(m0, __shfl_xor(m0, o)); m1 = fmaxf(m1, __shfl_xor(m1, o));
      m2 = fmaxf(m2, __shfl_xor(m2, o)); m3 = fmaxf(m3, __shfl_xor(m3, o));
    }
    float e0 = __expf(l0 - m0), e1 = __expf(l1 - m1);
    float e2 = __expf(l2 - m2), e3 = __expf(l3 - m3);
    float t0 = e0, t1 = e1, t2 = e2, t3 = e3;
#pragma unroll
    for (int o = 1; o < 16; o <<= 1) {
      t0 += __shfl_xor(t0, o); t1 += __shfl_xor(t1, o);
      t2 += __shfl_xor(t2, o); t3 += __shfl_xor(t3, o);
    }
    float a0 = e0 / t0 + EPS_, a1 = e1 / t1 + EPS_;
    float a2 = e2 / t2 + EPS_, a3 = e3 / t3 + EPS_;
    dden += a0 + a1 + a2 + a3;
    uint2 pk;
    pk.x = pk2(a0, a1); pk.y = pk2(a2, a3);
    int s = lane & 15;
    int nn = w * 64 + u * 16 + (lane >> 4) * 4;
    *(uint2*)((char*)att + s * 528 + nn * 2) = pk;
  }
  dden += __shfl_xor(dden, 16);
  dden += __shfl_xor(dden, 32);
  if (lane < 16) redd[w][lane] = dden;
  __syncthreads();
  if (t < S_)
    den_part[((size_t)b * NCH_ + chunk) * S_ + t] =
        redd[0][t] + redd[1][t] + redd[2][t] + redd[3][t];

  // ---- phase B: updates[s][k] += att[s][n] * v[n][k] via MFMA ----
  f32x4 acc[2] = {};
#pragma unroll
  for (int ks = 0; ks < 8; ks++) {
    bf16x8 pa = *(const bf16x8*)((const char*)att + (lane & 15) * 528 +
                                 (ks * 32 + (lane >> 4) * 8) * 2);
    size_t nb = (size_t)b * 128 + chunk * 8 + ks;
#pragma unroll
    for (int j = 0; j < 2; j++) {
      bf16x8 vb = *(const bf16x8*)(v_frag + (nb * 8 + (w * 2 + j)) * 512 + lane * 8);
      acc[j] = __builtin_amdgcn_mfma_f32_16x16x32_bf16(pa, vb, acc[j], 0, 0, 0);
    }
  }
#pragma unroll
  for (int j = 0; j < 2; j++)
#pragma unroll
    for (int r = 0; r < 4; r++) {
      int s = (lane >> 4) * 4 + r;
      if (s < S_) {
        int k = w * 32 + j * 16 + (lane & 15);
        num_part[(((size_t)b * NCH_ + chunk) * S_ + s) * 128 + k] = acc[j][r];
      }
    }
}

// ---------------- K6: finalize updates, GRU, MLP -> slots (256 thr, split halves) ----------------
__global__ __launch_bounds__(256) void k6_final(const float* __restrict__ num_part,
                                                const float* __restrict__ den_part,
                                                float* __restrict__ slots,
                                                const float* __restrict__ wTih,
                                                const float* __restrict__ wThh,
                                                const float* __restrict__ b_ih,
                                                const float* __restrict__ b_hh,
                                                const float* __restrict__ lmw,
                                                const float* __restrict__ lmb,
                                                const float* __restrict__ w1T,
                                                const float* __restrict__ bb1,
                                                const float* __restrict__ w2T,
                                                const float* __restrict__ bb2) {
  int bs = blockIdx.x;
  int b = bs / S_, s = bs % S_;
  int t = threadIdx.x;
  int j = t & 127, half = t >> 7;
  __shared__ float u[128], h[128], gp[3][128], m[128], hid[256], sjs[128], op[128];
  __shared__ float red2a[2], red2b[2];

  if (half == 0) {
    float den = 0.f;
#pragma unroll
    for (int c = 0; c < NCH_; c++) den += den_part[((size_t)b * NCH_ + c) * S_ + s];
    float uj = 0.f;
#pragma unroll
    for (int c = 0; c < NCH_; c++) uj += num_part[(((size_t)b * NCH_ + c) * S_ + s) * 128 + j];
    u[j] = uj / den;
  } else {
    h[j] = slots[((size_t)b * S_ + s) * 128 + j];
  }
  __syncthreads();

  // half 0: gi dots (w_ih, input u); half 1: gh dots (w_hh, input h)
  {
    const float* wT = half ? wThh : wTih;
    const float* sv = half ? h : u;
    float g0 = 0.f, g1 = 0.f, g2 = 0.f;
#pragma unroll 8
    for (int kk = 0; kk < 128; kk++) {
      float vv = sv[kk];
      const float* wr = wT + kk * 384;
      g0 += wr[j] * vv; g1 += wr[128 + j] * vv; g2 += wr[256 + j] * vv;
    }
    if (half) { gp[0][j] = g0; gp[1][j] = g1; gp[2][j] = g2; }
    __syncthreads();
    float sj = 0.f;
    if (half == 0) {
      float gr = g0 + b_ih[j]       + gp[0][j] + b_hh[j];
      float gz = g1 + b_ih[128 + j] + gp[1][j] + b_hh[128 + j];
      float r = 1.f / (1.f + __expf(-gr));
      float z = 1.f / (1.f + __expf(-gz));
      float nn = tanhf(g2 + b_ih[256 + j] + r * (gp[2][j] + b_hh[256 + j]));
      sj = (1.f - z) * nn + z * h[j];
      sjs[j] = sj;
    }
    // LN stats over half-0's 128 values (waves 0,1)
    float sv2 = sj, sq2 = sj * sj;
#pragma unroll
    for (int o = 1; o < 64; o <<= 1) { sv2 += __shfl_xor(sv2, o); sq2 += __shfl_xor(sq2, o); }
    if (half == 0 && (t & 63) == 0) { red2a[t >> 6] = sv2; red2b[t >> 6] = sq2; }
    __syncthreads();
    float mean = (red2a[0] + red2a[1]) * (1.f / 128.f);
    float var  = (red2b[0] + red2b[1]) * (1.f / 128.f) - mean * mean;
    float rstd = rsqrtf(var + LN_EPS_);
    if (half == 0) m[j] = (sj - mean) * rstd * lmw[j] + lmb[j];
  }
  __syncthreads();

  // MLP1: all 256 threads, one hidden unit each
  {
    float a = bb1[t];
#pragma unroll 8
    for (int kk = 0; kk < 128; kk++) a += w1T[kk * 256 + t] * m[kk];
    hid[t] = fmaxf(a, 0.f);
  }
  __syncthreads();

  // MLP2: half h sums hh in [h*128, h*128+128)
  {
    const float* w2p = w2T + (size_t)half * 128 * 128 + j;
    const float* hp = hid + half * 128;
    float o2 = 0.f;
#pragma unroll 8
    for (int q2 = 0; q2 < 128; q2++) o2 += w2p[q2 * 128] * hp[q2];
    if (half) op[j] = o2;
    __syncthreads();
    if (half == 0)
      slots[((size_t)b * S_ + s) * 128 + j] = sjs[j] + bb2[j] + o2 + op[j];
  }
}

// ---------------- copy out ----------------
__global__ __launch_bounds__(256) void k_copy(const float* __restrict__ slots,
                                              float* __restrict__ out) {
  int i = blockIdx.x * 256 + threadIdx.x;
  out[i] = slots[i];
}

extern "C" void kernel_launch(void* const* d_in, const int* in_sizes, int n_in,
                              void* d_out, int out_size, void* d_ws, size_t ws_size,
                              hipStream_t stream) {
  (void)in_sizes; (void)n_in; (void)out_size; (void)ws_size;
  const float* inputs     = (const float*)d_in[0];
  const float* slots_init = (const float*)d_in[1];
  const float* slots_mu   = (const float*)d_in[2];
  const float* slots_ls   = (const float*)d_in[3];
  const float* ln_in_w    = (const float*)d_in[4];
  const float* ln_in_b    = (const float*)d_in[5];
  const float* ln_slot_w  = (const float*)d_in[6];
  const float* ln_slot_b  = (const float*)d_in[7];
  const float* ln_mlp_w   = (const float*)d_in[8];
  const float* ln_mlp_b   = (const float*)d_in[9];
  const float* Wq         = (const float*)d_in[10];
  const float* Wk         = (const float*)d_in[11];
  const float* Wv         = (const float*)d_in[12];
  const float* w_ih       = (const float*)d_in[13];
  const float* w_hh       = (const float*)d_in[14];
  const float* b_ih       = (const float*)d_in[15];
  const float* b_hh       = (const float*)d_in[16];
  const float* mlp_w1     = (const float*)d_in[17];
  const float* mlp_b1     = (const float*)d_in[18];
  const float* mlp_w2     = (const float*)d_in[19];
  const float* mlp_b2     = (const float*)d_in[20];

  uintptr_t p = (uintptr_t)d_ws;
  auto carve = [&](size_t bytes) -> void* {
    void* r = (void*)p;
    p += (bytes + 255) & ~(size_t)255;
    return r;
  };
  unsigned short* k_frag = (unsigned short*)carve((size_t)B_ * N_ * K_ * 2);
  unsigned short* v_frag = (unsigned short*)carve((size_t)B_ * K_ * N_ * 2);
  unsigned short* W2pk   = (unsigned short*)carve((size_t)256 * 256 * 2);
  float* wTih  = (float*)carve((size_t)128 * 384 * 4);
  float* wThh  = (float*)carve((size_t)128 * 384 * 4);
  float* w1T   = (float*)carve((size_t)128 * 256 * 4);
  float* w2T   = (float*)carve((size_t)256 * 128 * 4);
  float* WqT   = (float*)carve((size_t)128 * 128 * 4);
  float* qbuf     = (float*)carve((size_t)B_ * S_ * K_ * 4);
  float* slots    = (float*)carve((size_t)B_ * S_ * K_ * 4);
  float* den_part = (float*)carve((size_t)B_ * NCH_ * S_ * 4);
  float* num_part = (float*)carve((size_t)B_ * NCH_ * S_ * K_ * 4);

  kprep<<<1088, 256, 0, stream>>>(Wk, Wv, W2pk, slots_init, slots_mu, slots_ls, slots,
                                  w_ih, w_hh, wTih, wThh, mlp_w1, w1T, mlp_w2, w2T,
                                  Wq, WqT);
  k12_lngemm<<<(B_ * N_) / 64, 256, 0, stream>>>(inputs, ln_in_w, ln_in_b, W2pk, k_frag, v_frag);

  for (int it = 0; it < ITERS_; ++it) {
    k3_q<<<B_ * S_, 128, 0, stream>>>(slots, ln_slot_w, ln_slot_b, WqT, qbuf);
    k45_attn<<<B_ * NCH_, 256, 0, stream>>>(k_frag, v_frag, qbuf, num_part, den_part);
    k6_final<<<B_ * S_, 256, 0, stream>>>(num_part, den_part, slots,
                                          wTih, wThh, b_ih, b_hh,
                                          ln_mlp_w, ln_mlp_b,
                                          w1T, mlp_b1, w2T, mlp_b2);
  }
  k_copy<<<(B_ * S_ * K_) / 256, 256, 0, stream>>>(slots, (float*)d_out);
}

// Round 5
// 286.237 us; speedup vs baseline: 4.6324x; 1.0080x over previous
//
#include <hip/hip_runtime.h>
#include <hip/hip_bf16.h>
#include <cstdint>
#include <cstddef>

#define B_ 64
#define N_ 4096
#define D_ 256
#define S_ 11
#define K_ 128
#define H_ 256
#define ITERS_ 3
#define EPS_ 1e-6f
#define LN_EPS_ 1e-5f
#define SCALE_ 0.08838834764831845f   // 128^-0.5
#define NCH_ 16                        // n-chunks per batch in k45

typedef __bf16 bf16x8 __attribute__((ext_vector_type(8)));
typedef float  f32x4  __attribute__((ext_vector_type(4)));

// native casts -> compiler emits v_cvt_pk_bf16_f32 (RTNE)
__device__ __forceinline__ unsigned short f2bu(float f) {
  __bf16 h = (__bf16)f;
  return __builtin_bit_cast(unsigned short, h);
}
__device__ __forceinline__ unsigned int pk2(float a, float b) {
  return (unsigned int)f2bu(a) | ((unsigned int)f2bu(b) << 16);
}

// ---------------- KPREP: W2 fragment-pack + slots init + weight transposes ----------------
// W2pk chunk f -> lane=f&63, j=(f>>6)&3, kk=(f>>8)&1, kt=(f>>9)&3, w=f>>11;
// element = W[row=w*64+j*16+(lane&15)][kt*64+kk*32+(lane>>4)*8 .. +8]; rows 0..127=Wk, 128..255=Wv
__global__ __launch_bounds__(256) void kprep(const float* __restrict__ Wk,
                                             const float* __restrict__ Wv,
                                             unsigned short* __restrict__ W2pk,
                                             const float* __restrict__ si,
                                             const float* __restrict__ mu,
                                             const float* __restrict__ ls,
                                             float* __restrict__ slots,
                                             const float* __restrict__ w_ih,
                                             const float* __restrict__ w_hh,
                                             float* __restrict__ wTih,
                                             float* __restrict__ wThh,
                                             const float* __restrict__ w1,
                                             float* __restrict__ w1T,
                                             const float* __restrict__ w2,
                                             float* __restrict__ w2T,
                                             const float* __restrict__ Wq,
                                             float* __restrict__ WqT) {
  int bid = blockIdx.x, t = threadIdx.x;
  if (bid < 32) {                        // W2pk: 8192 x 16B chunks
    int f = bid * 256 + t;
    int ln_ = f & 63, jj = (f >> 6) & 3, kk2 = (f >> 8) & 1, kt = (f >> 9) & 3, ww = f >> 11;
    int row = ww * 64 + jj * 16 + (ln_ & 15);
    int col = kt * 64 + kk2 * 32 + (ln_ >> 4) * 8;
    const float* src = (row < 128) ? (Wk + row * 256 + col) : (Wv + (row - 128) * 256 + col);
    float4 a = *(const float4*)src;
    float4 b = *(const float4*)(src + 4);
    uint4 u;
    u.x = pk2(a.x, a.y); u.y = pk2(a.z, a.w); u.z = pk2(b.x, b.y); u.w = pk2(b.z, b.w);
    *(uint4*)(W2pk + (size_t)f * 8) = u;
  } else if (bid < 384) {                // slots init: 90112
    int i = (bid - 32) * 256 + t;
    int k = i & 127;
    slots[i] = mu[k] + __expf(ls[k]) * si[i];
  } else if (bid < 576) {                // w_ih^T
    int i = (bid - 384) * 256 + t;
    int r = i >> 7, c = i & 127;
    wTih[c * 384 + r] = w_ih[i];
  } else if (bid < 768) {                // w_hh^T
    int i = (bid - 576) * 256 + t;
    int r = i >> 7, c = i & 127;
    wThh[c * 384 + r] = w_hh[i];
  } else if (bid < 896) {                // mlp_w1^T
    int i = (bid - 768) * 256 + t;
    int r = i >> 7, c = i & 127;
    w1T[c * 256 + r] = w1[i];
  } else if (bid < 1024) {               // mlp_w2^T
    int i = (bid - 896) * 256 + t;
    int r = i >> 8, c = i & 255;
    w2T[c * 128 + r] = w2[i];
  } else {                               // Wq^T
    int i = (bid - 1024) * 256 + t;
    int r = i >> 7, c = i & 127;
    WqT[c * 128 + r] = Wq[i];
  }
}

// ---------------- K12: fused LN(inputs) + split-orientation GEMM -> k_frag + v_frag ----------------
// 64 n-rows per block, 256 thr = 4 waves. Waves 0,1: D=Wk*x^T (rows=k-dim) -> direct global k_frag
// stores. Waves 2,3: D=x*Wv^T (rows=n) -> vs_st LDS -> coalesced v_frag stores.
__global__ __launch_bounds__(256) void k12_lngemm(const float* __restrict__ x,
                                                  const float* __restrict__ lnw,
                                                  const float* __restrict__ lnb,
                                                  const unsigned short* __restrict__ W2pk,
                                                  unsigned short* __restrict__ k_frag,
                                                  unsigned short* __restrict__ v_frag) {
  __shared__ char smem[32768];
  const int t = threadIdx.x;
  const int lane = t & 63, w = t >> 6;
  const long rowg0 = (long)blockIdx.x * 64;

  f32x4 acc[4][4] = {};
  bf16x8 bA[8], bB[8];
  auto loadB = [&](int kt, bf16x8* dst) {
#pragma unroll
    for (int kk = 0; kk < 2; kk++)
#pragma unroll
      for (int j = 0; j < 4; j++)
        dst[kk * 4 + j] =
            *(const bf16x8*)(W2pk + (size_t)(((((w * 4 + kt) * 2 + kk) * 4 + j) * 64) + lane) * 8);
  };

  loadB(0, bA);   // issue early; hides under LN

  // ---- LN: 16-lane groups, 4 rows per wave-iteration ----
  {
    const int sub = lane & 15, g2 = lane >> 4;
    float4 lw4[4], lb4[4];
#pragma unroll
    for (int q = 0; q < 4; q++) {
      lw4[q] = *(const float4*)(lnw + sub * 16 + q * 4);
      lb4[q] = *(const float4*)(lnb + sub * 16 + q * 4);
    }
#pragma unroll
    for (int it = 0; it < 4; it++) {
      int r = w * 16 + it * 4 + g2;
      const float* xr = x + (rowg0 + r) * 256 + sub * 16;
      float4 xv[4];
#pragma unroll
      for (int q = 0; q < 4; q++) xv[q] = *(const float4*)(xr + q * 4);
      float s = 0.f, sq = 0.f;
#pragma unroll
      for (int q = 0; q < 4; q++) {
        s  += xv[q].x + xv[q].y + xv[q].z + xv[q].w;
        sq += xv[q].x * xv[q].x + xv[q].y * xv[q].y + xv[q].z * xv[q].z + xv[q].w * xv[q].w;
      }
#pragma unroll
      for (int o = 1; o < 16; o <<= 1) { s += __shfl_xor(s, o); sq += __shfl_xor(sq, o); }
      float mean = s * (1.f / 256.f);
      float var  = sq * (1.f / 256.f) - mean * mean;
      float rstd = rsqrtf(var + LN_EPS_);
      uint4 u0, u1;
      u0.x = pk2((xv[0].x - mean) * rstd * lw4[0].x + lb4[0].x,
                 (xv[0].y - mean) * rstd * lw4[0].y + lb4[0].y);
      u0.y = pk2((xv[0].z - mean) * rstd * lw4[0].z + lb4[0].z,
                 (xv[0].w - mean) * rstd * lw4[0].w + lb4[0].w);
      u0.z = pk2((xv[1].x - mean) * rstd * lw4[1].x + lb4[1].x,
                 (xv[1].y - mean) * rstd * lw4[1].y + lb4[1].y);
      u0.w = pk2((xv[1].z - mean) * rstd * lw4[1].z + lb4[1].z,
                 (xv[1].w - mean) * rstd * lw4[1].w + lb4[1].w);
      u1.x = pk2((xv[2].x - mean) * rstd * lw4[2].x + lb4[2].x,
                 (xv[2].y - mean) * rstd * lw4[2].y + lb4[2].y);
      u1.y = pk2((xv[2].z - mean) * rstd * lw4[2].z + lb4[2].z,
                 (xv[2].w - mean) * rstd * lw4[2].w + lb4[2].w);
      u1.z = pk2((xv[3].x - mean) * rstd * lw4[3].x + lb4[3].x,
                 (xv[3].y - mean) * rstd * lw4[3].y + lb4[3].y);
      u1.w = pk2((xv[3].z - mean) * rstd * lw4[3].z + lb4[3].z,
                 (xv[3].w - mean) * rstd * lw4[3].w + lb4[3].w);
      int c0 = sub * 2;
      *(uint4*)(smem + r * 512 + ((c0 ^ (r & 7)) << 4)) = u0;
      *(uint4*)(smem + r * 512 + (((c0 + 1) ^ (r & 7)) << 4)) = u1;
    }
  }
  __syncthreads();   // As ready; read-only below

  auto compute = [&](int kt, const bf16x8* bf) {
#pragma unroll
    for (int kk = 0; kk < 2; kk++) {
      bf16x8 xf[4];
#pragma unroll
      for (int i = 0; i < 4; i++) {
        int row = i * 16 + (lane & 15);
        int slot = (kt * 8 + kk * 4 + (lane >> 4)) ^ (lane & 7);
        xf[i] = *(const bf16x8*)(smem + row * 512 + (slot << 4));
      }
      if (w < 2) {          // k-half: D rows = k-dim
#pragma unroll
        for (int j = 0; j < 4; j++)
#pragma unroll
          for (int i = 0; i < 4; i++)
            acc[j][i] = __builtin_amdgcn_mfma_f32_16x16x32_bf16(bf[kk * 4 + j], xf[i], acc[j][i], 0, 0, 0);
      } else {              // v-half: D rows = n
#pragma unroll
        for (int i = 0; i < 4; i++)
#pragma unroll
          for (int j = 0; j < 4; j++)
            acc[i][j] = __builtin_amdgcn_mfma_f32_16x16x32_bf16(xf[i], bf[kk * 4 + j], acc[i][j], 0, 0, 0);
      }
    }
  };

  loadB(1, bB); compute(0, bA);
  loadB(2, bA); compute(1, bB);
  loadB(3, bB); compute(2, bA);
  compute(3, bB);

  __syncthreads();   // all As reads done before smem reuse
  if (w < 2) {
    // ---- k-half: direct coalesced global stores (512B contiguous per instr) ----
    const int g = lane >> 4;
    unsigned short* kb = k_frag + (size_t)(rowg0 >> 4) * 2048;
#pragma unroll
    for (int j = 0; j < 4; j++)
#pragma unroll
      for (int i = 0; i < 4; i++) {
        uint2 pk;
        pk.x = pk2(acc[j][i][0], acc[j][i][1]);
        pk.y = pk2(acc[j][i][2], acc[j][i][3]);
        size_t el = (size_t)(i * 4 + w * 2 + (j >> 1)) * 512
                  + (2 * (j & 1) + (g >> 1)) * 128 + (lane & 15) * 8 + 4 * (g & 1);
        *(uint2*)(kb + el) = pk;
      }
  } else {
    // ---- v-half: stage transposed in LDS ----
    char* vs = smem;                    // [128 k] rows of 144B
#pragma unroll
    for (int i = 0; i < 4; i++)
#pragma unroll
      for (int j = 0; j < 4; j++) {
        int k = (w - 2) * 64 + j * 16 + (lane & 15);
        int n = i * 16 + (lane >> 4) * 4;
        uint2 pk;
        pk.x = pk2(acc[i][j][0], acc[i][j][1]);
        pk.y = pk2(acc[i][j][2], acc[i][j][3]);
        *(uint2*)(vs + k * 144 + n * 2) = pk;
      }
  }
  __syncthreads();
  // ---- v_frag store: 1024 chunks of 16B, coalesced ----
#pragma unroll
  for (int i = 0; i < 4; i++) {
    int f = i * 256 + t;
    int ln_ = f & 63, kt_ = (f >> 6) & 7, nb = f >> 9;
    int k = kt_ * 16 + (ln_ & 15);
    uint4 val = *(const uint4*)(smem + k * 144 + nb * 64 + (ln_ >> 4) * 16);
    *(uint4*)(v_frag + (size_t)(((rowg0 >> 5) + nb) * 8 + kt_) * 512 + ln_ * 8) = val;
  }
}

// ---------------- reduce helper: sum over 128 threads ----------------
__device__ __forceinline__ float redsum128(float v, float* red2) {
#pragma unroll
  for (int o = 1; o < 64; o <<= 1) v += __shfl_xor(v, o);
  __syncthreads();
  if ((threadIdx.x & 63) == 0) red2[threadIdx.x >> 6] = v;
  __syncthreads();
  return red2[0] + red2[1];
}

// ---------------- K3: initial q (iter 0 only) ----------------
__global__ __launch_bounds__(128) void k3_q(const float* __restrict__ slots,
                                            const float* __restrict__ lw,
                                            const float* __restrict__ lb,
                                            const float* __restrict__ WqT,
                                            float* __restrict__ q) {
  int bs = blockIdx.x;
  int j = threadIdx.x;
  __shared__ float sn[128];
  __shared__ float red2[2];
  float x = slots[(size_t)bs * 128 + j];
  float sum = redsum128(x, red2);
  float sq  = redsum128(x * x, red2);
  float mean = sum * (1.f / 128.f);
  float var  = sq * (1.f / 128.f) - mean * mean;
  float v = (x - mean) * rsqrtf(var + LN_EPS_) * lw[j] + lb[j];
  sn[j] = v;
  __syncthreads();
  float acc = 0.f;
#pragma unroll 8
  for (int kk = 0; kk < 128; kk++) acc += sn[kk] * WqT[kk * 128 + j];
  q[(size_t)bs * 128 + j] = acc;
}

// ---------------- K45: logits(MFMA) + softmax + updates(MFMA), fragment inputs ----------------
__global__ __launch_bounds__(256) void k45_attn(const unsigned short* __restrict__ k_frag,
                                                const unsigned short* __restrict__ v_frag,
                                                const float* __restrict__ qbuf,
                                                float* __restrict__ num_part,
                                                float* __restrict__ den_part) {
  __shared__ unsigned short att[16 * 264];   // stride 264 bf16 (528B)
  __shared__ float redd[4][16];
  const int t = threadIdx.x;
  const int lane = t & 63, w = t >> 6;
  const int b = blockIdx.x >> 4, chunk = blockIdx.x & (NCH_ - 1);

  int sqi = lane & 15; if (sqi > 10) sqi = 10;
  const float* qp = qbuf + ((size_t)b * S_ + sqi) * 128 + (lane >> 4) * 8;
  bf16x8 qf[4];
#pragma unroll
  for (int ks = 0; ks < 4; ks++) {
    float4 q0 = *(const float4*)(qp + ks * 32);
    float4 q1 = *(const float4*)(qp + ks * 32 + 4);
    uint4 uu;
    uu.x = pk2(q0.x, q0.y); uu.y = pk2(q0.z, q0.w);
    uu.z = pk2(q1.x, q1.y); uu.w = pk2(q1.z, q1.w);
    qf[ks] = __builtin_bit_cast(bf16x8, uu);
  }
  const bool dead = (lane & 15) >= 11;
  float dden = 0.f;

#pragma unroll
  for (int u = 0; u < 4; u++) {
    size_t g = (size_t)b * 256 + chunk * 16 + w * 4 + u;
    f32x4 lg = {0.f, 0.f, 0.f, 0.f};
#pragma unroll
    for (int ks = 0; ks < 4; ks++) {
      bf16x8 af = *(const bf16x8*)(k_frag + (g * 4 + ks) * 512 + lane * 8);
      lg = __builtin_amdgcn_mfma_f32_16x16x32_bf16(af, qf[ks], lg, 0, 0, 0);
    }
    float l0 = dead ? -1e30f : lg[0] * SCALE_;
    float l1 = dead ? -1e30f : lg[1] * SCALE_;
    float l2 = dead ? -1e30f : lg[2] * SCALE_;
    float l3 = dead ? -1e30f : lg[3] * SCALE_;
    float m0 = l0, m1 = l1, m2 = l2, m3 = l3;
#pragma unroll
    for (int o = 1; o < 16; o <<= 1) {
      m0 = fmaxf(m0, __shfl_xor(m0, o)); m1 = fmaxf(m1, __shfl_xor(m1, o));
      m2 = fmaxf(m2, __shfl_xor(m2, o)); m3 = fmaxf(m3, __shfl_xor(m3, o));
    }
    float e0 = __expf(l0 - m0), e1 = __expf(l1 - m1);
    float e2 = __expf(l2 - m2), e3 = __expf(l3 - m3);
    float t0 = e0, t1 = e1, t2 = e2, t3 = e3;
#pragma unroll
    for (int o = 1; o < 16; o <<= 1) {
      t0 += __shfl_xor(t0, o); t1 += __shfl_xor(t1, o);
      t2 += __shfl_xor(t2, o); t3 += __shfl_xor(t3, o);
    }
    float a0 = e0 / t0 + EPS_, a1 = e1 / t1 + EPS_;
    float a2 = e2 / t2 + EPS_, a3 = e3 / t3 + EPS_;
    dden += a0 + a1 + a2 + a3;
    uint2 pk;
    pk.x = pk2(a0, a1); pk.y = pk2(a2, a3);
    int s = lane & 15;
    int nn = w * 64 + u * 16 + (lane >> 4) * 4;
    *(uint2*)((char*)att + s * 528 + nn * 2) = pk;
  }
  dden += __shfl_xor(dden, 16);
  dden += __shfl_xor(dden, 32);
  if (lane < 16) redd[w][lane] = dden;
  __syncthreads();
  if (t < S_)
    den_part[((size_t)b * NCH_ + chunk) * S_ + t] =
        redd[0][t] + redd[1][t] + redd[2][t] + redd[3][t];

  f32x4 acc[2] = {};
#pragma unroll
  for (int ks = 0; ks < 8; ks++) {
    bf16x8 pa = *(const bf16x8*)((const char*)att + (lane & 15) * 528 +
                                 (ks * 32 + (lane >> 4) * 8) * 2);
    size_t nb = (size_t)b * 128 + chunk * 8 + ks;
#pragma unroll
    for (int j = 0; j < 2; j++) {
      bf16x8 vb = *(const bf16x8*)(v_frag + (nb * 8 + (w * 2 + j)) * 512 + lane * 8);
      acc[j] = __builtin_amdgcn_mfma_f32_16x16x32_bf16(pa, vb, acc[j], 0, 0, 0);
    }
  }
#pragma unroll
  for (int j = 0; j < 2; j++)
#pragma unroll
    for (int r = 0; r < 4; r++) {
      int s = (lane >> 4) * 4 + r;
      if (s < S_) {
        int k = w * 32 + j * 16 + (lane & 15);
        num_part[(((size_t)b * NCH_ + chunk) * S_ + s) * 128 + k] = acc[j][r];
      }
    }
}

// ---------------- K63: finalize updates, GRU, MLP -> slots (+fused next-iter q, +d_out) ----------------
__global__ __launch_bounds__(256) void k63_final(const float* __restrict__ num_part,
                                                 const float* __restrict__ den_part,
                                                 float* __restrict__ slots,
                                                 const float* __restrict__ wTih,
                                                 const float* __restrict__ wThh,
                                                 const float* __restrict__ b_ih,
                                                 const float* __restrict__ b_hh,
                                                 const float* __restrict__ lmw,
                                                 const float* __restrict__ lmb,
                                                 const float* __restrict__ w1T,
                                                 const float* __restrict__ bb1,
                                                 const float* __restrict__ w2T,
                                                 const float* __restrict__ bb2,
                                                 const float* __restrict__ lsw,
                                                 const float* __restrict__ lsb,
                                                 const float* __restrict__ WqT,
                                                 float* __restrict__ qbuf,
                                                 float* __restrict__ outp,
                                                 int cq, int wout) {
  int bs = blockIdx.x;
  int b = bs / S_, s = bs % S_;
  int t = threadIdx.x;
  int j = t & 127, half = t >> 7;
  __shared__ float u[128], h[128], gp[3][128], m[128], hid[256], sjs[128], op[128];
  __shared__ float ns[128], snq[128];
  __shared__ float red2a[2], red2b[2];

  if (half == 0) {
    float den = 0.f;
#pragma unroll
    for (int c = 0; c < NCH_; c++) den += den_part[((size_t)b * NCH_ + c) * S_ + s];
    float uj = 0.f;
#pragma unroll
    for (int c = 0; c < NCH_; c++) uj += num_part[(((size_t)b * NCH_ + c) * S_ + s) * 128 + j];
    u[j] = uj / den;
  } else {
    h[j] = slots[((size_t)b * S_ + s) * 128 + j];
  }
  __syncthreads();

  {
    const float* wT = half ? wThh : wTih;
    const float* sv = half ? h : u;
    float g0 = 0.f, g1 = 0.f, g2 = 0.f;
#pragma unroll 8
    for (int kk = 0; kk < 128; kk++) {
      float vv = sv[kk];
      const float* wr = wT + kk * 384;
      g0 += wr[j] * vv; g1 += wr[128 + j] * vv; g2 += wr[256 + j] * vv;
    }
    if (half) { gp[0][j] = g0; gp[1][j] = g1; gp[2][j] = g2; }
    __syncthreads();
    float sj = 0.f;
    if (half == 0) {
      float gr = g0 + b_ih[j]       + gp[0][j] + b_hh[j];
      float gz = g1 + b_ih[128 + j] + gp[1][j] + b_hh[128 + j];
      float r = 1.f / (1.f + __expf(-gr));
      float z = 1.f / (1.f + __expf(-gz));
      float nn = tanhf(g2 + b_ih[256 + j] + r * (gp[2][j] + b_hh[256 + j]));
      sj = (1.f - z) * nn + z * h[j];
      sjs[j] = sj;
    }
    float sv2 = sj, sq2 = sj * sj;
#pragma unroll
    for (int o = 1; o < 64; o <<= 1) { sv2 += __shfl_xor(sv2, o); sq2 += __shfl_xor(sq2, o); }
    if (half == 0 && (t & 63) == 0) { red2a[t >> 6] = sv2; red2b[t >> 6] = sq2; }
    __syncthreads();
    float mean = (red2a[0] + red2a[1]) * (1.f / 128.f);
    float var  = (red2b[0] + red2b[1]) * (1.f / 128.f) - mean * mean;
    float rstd = rsqrtf(var + LN_EPS_);
    if (half == 0) m[j] = (sj - mean) * rstd * lmw[j] + lmb[j];
  }
  __syncthreads();

  {
    float a = bb1[t];
#pragma unroll 8
    for (int kk = 0; kk < 128; kk++) a += w1T[kk * 256 + t] * m[kk];
    hid[t] = fmaxf(a, 0.f);
  }
  __syncthreads();

  {
    const float* w2p = w2T + (size_t)half * 128 * 128 + j;
    const float* hp = hid + half * 128;
    float o2 = 0.f;
#pragma unroll 8
    for (int q2 = 0; q2 < 128; q2++) o2 += w2p[q2 * 128] * hp[q2];
    if (half) op[j] = o2;
    __syncthreads();
    if (half == 0) {
      float ov = sjs[j] + bb2[j] + o2 + op[j];
      slots[((size_t)b * S_ + s) * 128 + j] = ov;
      if (wout) outp[((size_t)b * S_ + s) * 128 + j] = ov;
      ns[j] = ov;
    }
  }
  __syncthreads();

  if (cq) {   // fused q for next iteration: q = LN_slot(new_slots) * Wq^T
    float vv = (half == 0) ? ns[j] : 0.f;
    float s1 = vv, s2 = vv * vv;
#pragma unroll
    for (int o = 1; o < 64; o <<= 1) { s1 += __shfl_xor(s1, o); s2 += __shfl_xor(s2, o); }
    if (half == 0 && (t & 63) == 0) { red2a[t >> 6] = s1; red2b[t >> 6] = s2; }
    __syncthreads();
    float mean = (red2a[0] + red2a[1]) * (1.f / 128.f);
    float var  = (red2b[0] + red2b[1]) * (1.f / 128.f) - mean * mean;
    float rstd = rsqrtf(var + LN_EPS_);
    if (half == 0) snq[j] = (ns[j] - mean) * rstd * lsw[j] + lsb[j];
    __syncthreads();
    const float* wq = WqT + (size_t)half * 64 * 128;
    const float* sp = snq + half * 64;
    float qv = 0.f;
#pragma unroll 8
    for (int kk = 0; kk < 64; kk++) qv += wq[kk * 128 + j] * sp[kk];
    if (half) op[j] = qv;
    __syncthreads();
    if (half == 0) qbuf[(size_t)bs * 128 + j] = qv + op[j];
  }
}

extern "C" void kernel_launch(void* const* d_in, const int* in_sizes, int n_in,
                              void* d_out, int out_size, void* d_ws, size_t ws_size,
                              hipStream_t stream) {
  (void)in_sizes; (void)n_in; (void)out_size; (void)ws_size;
  const float* inputs     = (const float*)d_in[0];
  const float* slots_init = (const float*)d_in[1];
  const float* slots_mu   = (const float*)d_in[2];
  const float* slots_ls   = (const float*)d_in[3];
  const float* ln_in_w    = (const float*)d_in[4];
  const float* ln_in_b    = (const float*)d_in[5];
  const float* ln_slot_w  = (const float*)d_in[6];
  const float* ln_slot_b  = (const float*)d_in[7];
  const float* ln_mlp_w   = (const float*)d_in[8];
  const float* ln_mlp_b   = (const float*)d_in[9];
  const float* Wq         = (const float*)d_in[10];
  const float* Wk         = (const float*)d_in[11];
  const float* Wv         = (const float*)d_in[12];
  const float* w_ih       = (const float*)d_in[13];
  const float* w_hh       = (const float*)d_in[14];
  const float* b_ih       = (const float*)d_in[15];
  const float* b_hh       = (const float*)d_in[16];
  const float* mlp_w1     = (const float*)d_in[17];
  const float* mlp_b1     = (const float*)d_in[18];
  const float* mlp_w2     = (const float*)d_in[19];
  const float* mlp_b2     = (const float*)d_in[20];

  uintptr_t p = (uintptr_t)d_ws;
  auto carve = [&](size_t bytes) -> void* {
    void* r = (void*)p;
    p += (bytes + 255) & ~(size_t)255;
    return r;
  };
  unsigned short* k_frag = (unsigned short*)carve((size_t)B_ * N_ * K_ * 2);
  unsigned short* v_frag = (unsigned short*)carve((size_t)B_ * K_ * N_ * 2);
  unsigned short* W2pk   = (unsigned short*)carve((size_t)256 * 256 * 2);
  float* wTih  = (float*)carve((size_t)128 * 384 * 4);
  float* wThh  = (float*)carve((size_t)128 * 384 * 4);
  float* w1T   = (float*)carve((size_t)128 * 256 * 4);
  float* w2T   = (float*)carve((size_t)256 * 128 * 4);
  float* WqT   = (float*)carve((size_t)128 * 128 * 4);
  float* qbuf     = (float*)carve((size_t)B_ * S_ * K_ * 4);
  float* slots    = (float*)carve((size_t)B_ * S_ * K_ * 4);
  float* den_part = (float*)carve((size_t)B_ * NCH_ * S_ * 4);
  float* num_part = (float*)carve((size_t)B_ * NCH_ * S_ * K_ * 4);

  kprep<<<1088, 256, 0, stream>>>(Wk, Wv, W2pk, slots_init, slots_mu, slots_ls, slots,
                                  w_ih, w_hh, wTih, wThh, mlp_w1, w1T, mlp_w2, w2T,
                                  Wq, WqT);
  k12_lngemm<<<(B_ * N_) / 64, 256, 0, stream>>>(inputs, ln_in_w, ln_in_b, W2pk, k_frag, v_frag);
  k3_q<<<B_ * S_, 128, 0, stream>>>(slots, ln_slot_w, ln_slot_b, WqT, qbuf);

  for (int it = 0; it < ITERS_; ++it) {
    k45_attn<<<B_ * NCH_, 256, 0, stream>>>(k_frag, v_frag, qbuf, num_part, den_part);
    k63_final<<<B_ * S_, 256, 0, stream>>>(num_part, den_part, slots,
                                           wTih, wThh, b_ih, b_hh,
                                           ln_mlp_w, ln_mlp_b,
                                           w1T, mlp_b1, w2T, mlp_b2,
                                           ln_slot_w, ln_slot_b, WqT, qbuf,
                                           (float*)d_out,
                                           (it < ITERS_ - 1) ? 1 : 0,
                                           (it == ITERS_ - 1) ? 1 : 0);
  }
}